// Round 10
// baseline (372.907 us; speedup 1.0000x reference)
//
#include <hip/hip_runtime.h>
#include <hip/hip_bf16.h>

#define D_MODEL 1024
#define N_HEADS 16
#define HEAD_DIM 64
#define NUM_RULES 64
#define RANK 8
#define SHARED_RANK 32
#define NUM_BLOCKS_ 16
#define BB 4
#define SS 1024
#define NTOK (BB*SS)
#define NGRP (NTOK/8)   // 512 token-groups of 8

__device__ __forceinline__ float bf2f(unsigned short u) {
  unsigned int i = ((unsigned int)u) << 16;
  float f;
  __builtin_memcpy(&f, &i, 4);
  return f;
}
__device__ __forceinline__ unsigned short f2bf(float f) {
  __hip_bfloat16 h = __float2bfloat16(f);
  unsigned short u;
  __builtin_memcpy(&u, &h, 2);
  return u;
}
__device__ __forceinline__ float u2f(unsigned int i) {
  float f;
  __builtin_memcpy(&f, &i, 4);
  return f;
}
template<bool BF>
__device__ __forceinline__ float ldw(const void* p, size_t i) {
  if (BF) return bf2f(((const unsigned short*)p)[i]);
  else    return ((const float*)p)[i];
}

// ---------------------------------------------------------------------------
// Dtype detection
// ---------------------------------------------------------------------------
__global__ void detect_kernel(const unsigned short* __restrict__ x, int* __restrict__ flag) {
  const int lane = threadIdx.x;  // 64
  int good = 0;
  for (int i = 0; i < 4; i++) {
    unsigned short u = x[lane*4 + i];
    int e = (u >> 7) & 0xFF;
    good += (e == 0 || (e >= 100 && e <= 145)) ? 1 : 0;
  }
  for (int off = 32; off; off >>= 1) good += __shfl_xor(good, off);
  if (lane == 0) flag[0] = (good >= 224) ? 1 : 0;
}

// ---------------------------------------------------------------------------
// Precompute: M[64][64] and sel[4][64][16]
// ---------------------------------------------------------------------------
template<bool BF>
__device__ __forceinline__ void precompute_body(
    const void* rq, const void* rk,
    const void* qlg, const void* klg, const void* vlg, const void* olg,
    float* __restrict__ M, float* __restrict__ sel)
{
  __shared__ float rqn[64][8], rkn[64][8];
  const int tid = threadIdx.x;  // 256
  if (tid < 64) {
    float v[8]; float s = 0.f;
    for (int i = 0; i < 8; i++) { v[i] = ldw<BF>(rq, tid*8+i); s += v[i]*v[i]; }
    float inv = 1.0f / fmaxf(sqrtf(s), 1e-12f);
    for (int i = 0; i < 8; i++) rqn[tid][i] = v[i]*inv;
  } else if (tid < 128) {
    int r = tid - 64;
    float v[8]; float s = 0.f;
    for (int i = 0; i < 8; i++) { v[i] = ldw<BF>(rk, r*8+i); s += v[i]*v[i]; }
    float inv = 1.0f / fmaxf(sqrtf(s), 1e-12f);
    for (int i = 0; i < 8; i++) rkn[r][i] = v[i]*inv;
  }
  __syncthreads();
  const float LN8 = 2.0794415416798357f;  // 1/tau = ln(8)
  for (int idx = tid; idx < 64*64; idx += 256) {
    int i = idx >> 6, j = idx & 63;
    float d = 0.f;
    for (int t = 0; t < 8; t++) d += rqn[i][t]*rkn[j][t];
    M[idx] = d * LN8;
  }
  const void* lgs[4] = {qlg, klg, vlg, olg};
  {
    int r = tid & 63;
    const void* lg = lgs[tid >> 6];
    float e[NUM_BLOCKS_]; float mx = -1e30f;
    for (int b = 0; b < NUM_BLOCKS_; b++) {
      e[b] = ldw<BF>(lg, r*NUM_BLOCKS_ + b) * 4.0f;
      mx = fmaxf(mx, e[b]);
    }
    float s = 0.f;
    for (int b = 0; b < NUM_BLOCKS_; b++) { e[b] = expf(e[b]-mx); s += e[b]; }
    float inv = 1.0f/s;
    for (int b = 0; b < NUM_BLOCKS_; b++) sel[tid*NUM_BLOCKS_+b] = e[b]*inv;
  }
}

__global__ void precompute_kernel(
    const void* rq, const void* rk,
    const void* qlg, const void* klg, const void* vlg, const void* olg,
    float* M, float* sel, const int* __restrict__ flag)
{
  if (*flag) precompute_body<true >(rq, rk, qlg, klg, vlg, olg, M, sel);
  else       precompute_body<false>(rq, rk, qlg, klg, vlg, olg, M, sel);
}

// ---------------------------------------------------------------------------
// FUSED projection (stage A + stage B in one kernel; tt/hh via LDS).
// 8 tokens/block, 256 threads. ONE instantiation per __global__ (LDS/VGPR
// discipline — R3 lesson).  Phase A: tt = x@si, hh = per-rule lowrank.
// Phase B: out = tt@so + sel*(hh@ro), optional RoPE, fp32/bf16 store.
// ---------------------------------------------------------------------------
template<bool IN_BF, bool W_BF>
__device__ __forceinline__ void stageAB_body(
    const void* __restrict__ xin, const int* __restrict__ rules,
    const void* __restrict__ si, const void* __restrict__ ri,
    const void* __restrict__ so, const void* __restrict__ ro,
    const float* __restrict__ sel, void* __restrict__ out,
    int do_rope, int out_bf)
{
  const int g = blockIdx.x, n0 = g*8, tid = threadIdx.x;
  __shared__ float xs[8][D_MODEL];     // 32 KB
  __shared__ float tpart[8][32][9];    // 9.2 KB, pad 9: conflict-free reduce
  __shared__ float tt_lds[32][9];      // [j][t]
  __shared__ float hh_lds[8][132];     // [t][blk*8+r]
  __shared__ int rl[8];

  // ---- A: load x rows ----
  #pragma unroll
  for (int t = 0; t < 8; t++) {
    float4 f;
    if (IN_BF) {
      ushort4 u = ((const ushort4*)((const unsigned short*)xin + (size_t)(n0+t)*D_MODEL))[tid];
      f.x = bf2f(u.x); f.y = bf2f(u.y); f.z = bf2f(u.z); f.w = bf2f(u.w);
    } else {
      f = ((const float4*)xin)[(size_t)(n0+t)*(D_MODEL/4) + tid];
    }
    *(float4*)&xs[t][tid*4] = f;
  }
  if (tid < 8) rl[tid] = rules[n0 + tid];
  __syncthreads();

  // ---- A: tpart[c][j][t] partial dots ----
  {
    const int c = tid >> 5, j = tid & 31;
    float p[8];
    #pragma unroll
    for (int t = 0; t < 8; t++) p[t] = 0.f;
    for (int d4 = 0; d4 < 32; d4++) {
      const int d = c*128 + d4*4;
      float w0 = ldw<W_BF>(si, (size_t)(d+0)*SHARED_RANK + j);
      float w1 = ldw<W_BF>(si, (size_t)(d+1)*SHARED_RANK + j);
      float w2 = ldw<W_BF>(si, (size_t)(d+2)*SHARED_RANK + j);
      float w3 = ldw<W_BF>(si, (size_t)(d+3)*SHARED_RANK + j);
      #pragma unroll
      for (int t = 0; t < 8; t++) {
        float4 xv = *(const float4*)&xs[t][d];   // broadcast across j-lanes
        p[t] += xv.x*w0 + xv.y*w1 + xv.z*w2 + xv.w*w3;
      }
    }
    #pragma unroll
    for (int t = 0; t < 8; t++) tpart[c][j][t] = p[t];
  }
  __syncthreads();

  // ---- A: reduce tt into LDS ----
  {
    const int t = tid >> 5, j = tid & 31;
    float s = 0.f;
    #pragma unroll
    for (int c = 0; c < 8; c++) s += tpart[c][j][t];
    tt_lds[j][t] = s;
  }
  // ---- A: hh into LDS ----
  {
    const int t = tid >> 5, blk = (tid >> 1) & 15, r0 = (tid & 1)*4;
    const int rule = rl[t];
    float a0=0.f, a1=0.f, a2=0.f, a3=0.f;
    for (int k4 = 0; k4 < 16; k4++) {
      const int kk = ((k4 + blk) & 15) * 4;   // rotate: spreads LDS banks
      float4 xv = *(const float4*)&xs[t][blk*64 + kk];
      #pragma unroll
      for (int q = 0; q < 4; q++) {
        const int k = kk + q;
        float w0,w1,w2,w3;
        if (W_BF) {
          ushort4 u = *(const ushort4*)((const unsigned short*)ri + (size_t)rule*512 + (size_t)k*8 + r0);
          w0=bf2f(u.x); w1=bf2f(u.y); w2=bf2f(u.z); w3=bf2f(u.w);
        } else {
          float4 u = *(const float4*)((const float*)ri + (size_t)rule*512 + (size_t)k*8 + r0);
          w0=u.x; w1=u.y; w2=u.z; w3=u.w;
        }
        float xq = (q==0)?xv.x:((q==1)?xv.y:((q==2)?xv.z:xv.w));
        a0 += xq*w0; a1 += xq*w1; a2 += xq*w2; a3 += xq*w3;
      }
    }
    float4 hv; hv.x=a0; hv.y=a1; hv.z=a2; hv.w=a3;
    *(float4*)&hh_lds[t][blk*8 + r0] = hv;
  }
  __syncthreads();

  // ---- B: thread = 4 consecutive channels ----
  const int ch0 = tid*4;
  float a0[8], a1[8], a2[8], a3[8];
  #pragma unroll
  for (int t = 0; t < 8; t++) { a0[t]=0.f; a1[t]=0.f; a2[t]=0.f; a3[t]=0.f; }

  for (int j = 0; j < 32; j++) {
    float w0, w1, w2, w3;
    if (W_BF) {
      ushort4 u = *(const ushort4*)((const unsigned short*)so + (size_t)j*D_MODEL + ch0);
      w0=bf2f(u.x); w1=bf2f(u.y); w2=bf2f(u.z); w3=bf2f(u.w);
    } else {
      float4 u = *(const float4*)((const float*)so + (size_t)j*D_MODEL + ch0);
      w0=u.x; w1=u.y; w2=u.z; w3=u.w;
    }
    #pragma unroll
    for (int t = 0; t < 8; t++) {
      float tv = tt_lds[j][t];         // LDS broadcast
      a0[t] += tv*w0; a1[t] += tv*w1; a2[t] += tv*w2; a3[t] += tv*w3;
    }
  }

  const int blk = ch0 >> 6, tc = ch0 & 63;
  float inv0 = 0.f, inv1 = 0.f;
  if (do_rope) {
    inv0 = expf(-(float)tc     * (9.210340371976184f/64.0f));   // 2*i0 == tc
    inv1 = expf(-(float)(tc+2) * (9.210340371976184f/64.0f));
  }
  #pragma unroll
  for (int t = 0; t < 8; t++) {
    const int rule = rl[t];
    float b0=0.f, b1=0.f, b2=0.f, b3=0.f;
    #pragma unroll
    for (int r = 0; r < 8; r++) {
      float w0,w1,w2,w3;
      if (W_BF) {
        ushort4 u = *(const ushort4*)((const unsigned short*)ro + (size_t)rule*512 + r*64 + tc);
        w0=bf2f(u.x); w1=bf2f(u.y); w2=bf2f(u.z); w3=bf2f(u.w);
      } else {
        float4 u = *(const float4*)((const float*)ro + (size_t)rule*512 + r*64 + tc);
        w0=u.x; w1=u.y; w2=u.z; w3=u.w;
      }
      float hv = hh_lds[t][blk*8 + r];
      b0 += hv*w0; b1 += hv*w1; b2 += hv*w2; b3 += hv*w3;
    }
    float sb = sel[rule*NUM_BLOCKS_ + blk];
    float e0 = a0[t] + b0*sb, o0 = a1[t] + b1*sb;
    float e1 = a2[t] + b2*sb, o1 = a3[t] + b3*sb;
    const int n = n0 + t;
    if (do_rope) {
      float spos = (float)(n & (SS-1));
      float sn0, cs0, sn1, cs1;
      sincosf(spos*inv0, &sn0, &cs0);
      sincosf(spos*inv1, &sn1, &cs1);
      float u0 = e0*cs0 - o0*sn0; o0 = o0*cs0 + e0*sn0; e0 = u0;
      float u1 = e1*cs1 - o1*sn1; o1 = o1*cs1 + e1*sn1; e1 = u1;
    }
    if (out_bf) {
      ushort4 uv; uv.x=f2bf(e0); uv.y=f2bf(o0); uv.z=f2bf(e1); uv.w=f2bf(o1);
      *(ushort4*)((unsigned short*)out + (size_t)n*D_MODEL + ch0) = uv;
    } else {
      float4 fv; fv.x=e0; fv.y=o0; fv.z=e1; fv.w=o1;
      *(float4*)((float*)out + (size_t)n*D_MODEL + ch0) = fv;
    }
  }
}

__global__ __launch_bounds__(256) void AB_qkv_bf16(
    const void* x, const int* rules,
    const void* qsi, const void* qri, const void* qso, const void* qro,
    const void* ksi, const void* kri, const void* kso, const void* kro,
    const void* vsi, const void* vri, const void* vso, const void* vro,
    const float* sel, float* qb, unsigned short* kb, unsigned short* vb,
    const int* __restrict__ flag)
{
  if (!*flag) return;
  const int y = blockIdx.y;
  const void* si = (y==0)?qsi:((y==1)?ksi:vsi);
  const void* ri = (y==0)?qri:((y==1)?kri:vri);
  const void* so = (y==0)?qso:((y==1)?kso:vso);
  const void* ro = (y==0)?qro:((y==1)?kro:vro);
  void* out = (y==0)?(void*)qb:((y==1)?(void*)kb:(void*)vb);
  stageAB_body<true,true>(x, rules, si, ri, so, ro, sel + y*1024, out, (y<2)?1:0, (y>=1)?1:0);
}

__global__ __launch_bounds__(256) void AB_qkv_f32(
    const void* x, const int* rules,
    const void* qsi, const void* qri, const void* qso, const void* qro,
    const void* ksi, const void* kri, const void* kso, const void* kro,
    const void* vsi, const void* vri, const void* vso, const void* vro,
    const float* sel, float* qb, unsigned short* kb, unsigned short* vb,
    const int* __restrict__ flag)
{
  if (*flag) return;
  const int y = blockIdx.y;
  const void* si = (y==0)?qsi:((y==1)?ksi:vsi);
  const void* ri = (y==0)?qri:((y==1)?kri:vri);
  const void* so = (y==0)?qso:((y==1)?kso:vso);
  const void* ro = (y==0)?qro:((y==1)?kro:vro);
  void* out = (y==0)?(void*)qb:((y==1)?(void*)kb:(void*)vb);
  stageAB_body<false,false>(x, rules, si, ri, so, ro, sel + y*1024, out, (y<2)?1:0, (y>=1)?1:0);
}

// o-projection: fp32 input (attn output), bf16/f32 weights, output to d_out
__global__ __launch_bounds__(256) void AB_o_bf16(
    const void* ain, const int* rules,
    const void* osi, const void* ori, const void* oso, const void* oro,
    const float* sel, void* out, const int* __restrict__ flag)
{
  if (!*flag) return;
  stageAB_body<false,true>(ain, rules, osi, ori, oso, oro, sel, out, 0, 1);
}

__global__ __launch_bounds__(256) void AB_o_f32(
    const void* ain, const int* rules,
    const void* osi, const void* ori, const void* oso, const void* oro,
    const float* sel, void* out, const int* __restrict__ flag)
{
  if (*flag) return;
  stageAB_body<false,false>(ain, rules, osi, ori, oso, oro, sel, out, 0, 0);
}

// ---------------------------------------------------------------------------
// Router mask — one 64-thread wave per (b,q); LDS-atomic histogram with
// barrier before read.
// ---------------------------------------------------------------------------
__global__ __launch_bounds__(64) void mask_kernel(
    const int* __restrict__ rules, const float* __restrict__ M,
    unsigned short* __restrict__ list, int* __restrict__ cntout)
{
  const int bid = blockIdx.x;              // b*1024 + qi
  const int b = bid >> 10, qi = bid & 1023;
  const int lane = threadIdx.x;
  __shared__ int rrow[SS];
  __shared__ float val[64];
  __shared__ int cnth[64];
  for (int i = lane; i < SS/4; i += 64)
    ((int4*)rrow)[i] = ((const int4*)(rules + b*SS))[i];
  cnth[lane] = 0;
  __syncthreads();                          // rrow + cnth=0 visible
  for (int k = lane; k <= qi; k += 64) atomicAdd(&cnth[rrow[k]], 1);
  const int qrule = rrow[qi];
  const float myv = M[qrule*64 + lane];
  val[lane] = myv;
  __syncthreads();                          // histogram + val visible
  const int c = cnth[lane];
  int A = 0;
  for (int r = 0; r < 64; r++) {
    int cr = __shfl(c, r);
    A += (val[r] > myv) ? cr : 0;
  }
  unsigned long long allowed = __ballot(A < 32);
  unsigned short* lp = list + (size_t)bid*SS;
  int pos = 0;
  const unsigned long long lmask = (1ULL << lane) - 1ULL;
  for (int k0 = 0; k0 <= qi; k0 += 64) {
    int k = k0 + lane;
    int kc = (k <= qi) ? k : qi;
    bool ok = (k <= qi) && (((allowed >> rrow[kc]) & 1ULL) != 0ULL);
    unsigned long long bal = __ballot(ok);
    if (ok) lp[pos + __popcll(bal & lmask)] = (unsigned short)k;
    pos += __popcll(bal);
  }
  if (lane == 0) cntout[bid] = pos;
}

// ---------------------------------------------------------------------------
// Sparse attention: block = (b, q, head-group of 4); 4 waves, one head each.
// keyl padded to a 64-multiple at staging -> PV loop has no clamp; every
// __shfl executes uniformly across all 64 lanes (R8 lesson: divergent-bound
// shfl loops are deterministic garbage). Explicit dword bf16 unpack.
// ---------------------------------------------------------------------------
__global__ __launch_bounds__(256) void attn_kernel(
    const float* __restrict__ qb,
    const unsigned short* __restrict__ kb, const unsigned short* __restrict__ vb,
    const unsigned short* __restrict__ list, const int* __restrict__ cnt,
    float* __restrict__ outb)
{
  const int qi = blockIdx.x, b = blockIdx.y, hg = blockIdx.z;
  const int tid = threadIdx.x, lane = tid & 63, w = tid >> 6;
  const int nq = b*SS + qi;
  const int h = hg*4 + w;
  __shared__ unsigned short keyl[SS + 64];
  __shared__ float qs[4][64];
  const int total = cnt[nq];
  const int padded = (total + 63) & ~63;
  const unsigned short* lp = list + (size_t)nq*SS;
  for (int i = tid; i < total; i += 256) keyl[i] = lp[i];
  if (total < padded) {
    unsigned short k0 = lp[0];
    for (int i = total + tid; i < padded; i += 256) keyl[i] = k0;
  }
  qs[w][lane] = qb[(size_t)nq*D_MODEL + h*HEAD_DIM + lane] * 0.125f;
  __syncthreads();

  const unsigned short* kbase = kb + (size_t)b*SS*D_MODEL + h*HEAD_DIM;
  const unsigned short* vbase = vb + (size_t)b*SS*D_MODEL + h*HEAD_DIM;
  const int g = lane >> 4, d4 = lane & 15;
  float4 acc = {0.f,0.f,0.f,0.f};
  float m = -1e30f, l = 0.f;
  for (int c0 = 0; c0 < total; c0 += 64) {
    int nc = total - c0; if (nc > 64) nc = 64;
    float s = -1e30f;
    if (lane < nc) {
      int key = keyl[c0 + lane];
      const uint2* kr = (const uint2*)(kbase + (size_t)key*D_MODEL);
      float sum = 0.f;
      #pragma unroll
      for (int t = 0; t < 16; t++) {
        uint2 kw = kr[t];
        float4 qv = *(const float4*)&qs[w][4*t];  // LDS broadcast
        sum += qv.x*u2f(kw.x << 16) + qv.y*u2f(kw.x & 0xffff0000u)
             + qv.z*u2f(kw.y << 16) + qv.w*u2f(kw.y & 0xffff0000u);
      }
      s = sum;
    }
    float cm = s;
    #pragma unroll
    for (int off = 32; off; off >>= 1) cm = fmaxf(cm, __shfl_xor(cm, off));
    float newm = fmaxf(m, cm);
    float alpha = expf(m - newm);
    float ww = (lane < nc) ? expf(s - newm) : 0.f;
    float lsum = ww;
    #pragma unroll
    for (int off = 32; off; off >>= 1) lsum += __shfl_xor(lsum, off);
    l = l*alpha + lsum;
    m = newm;
    acc.x *= alpha; acc.y *= alpha; acc.z *= alpha; acc.w *= alpha;
    // Uniform 16 iterations; keyl padded so indices are always valid and
    // ww==0 beyond nc; all shfl source lanes active.
    #pragma unroll 4
    for (int it = 0; it < 16; it++) {
      int i = g + it*4;
      float wi = __shfl(ww, i);
      int key = keyl[c0 + i];
      uint2 vw = *(const uint2*)(vbase + (size_t)key*D_MODEL + d4*4);
      acc.x += wi*u2f(vw.x << 16); acc.y += wi*u2f(vw.x & 0xffff0000u);
      acc.z += wi*u2f(vw.y << 16); acc.w += wi*u2f(vw.y & 0xffff0000u);
    }
  }
  acc.x += __shfl_xor(acc.x, 16); acc.y += __shfl_xor(acc.y, 16);
  acc.z += __shfl_xor(acc.z, 16); acc.w += __shfl_xor(acc.w, 16);
  acc.x += __shfl_xor(acc.x, 32); acc.y += __shfl_xor(acc.y, 32);
  acc.z += __shfl_xor(acc.z, 32); acc.w += __shfl_xor(acc.w, 32);
  if (lane < 16) {
    float invl = 1.0f / l;
    float4 o;
    o.x = acc.x*invl; o.y = acc.y*invl; o.z = acc.z*invl; o.w = acc.w*invl;
    *(float4*)(outb + (size_t)nq*D_MODEL + h*HEAD_DIM + d4*4) = o;
  }
}

// ---------------------------------------------------------------------------
extern "C" void kernel_launch(void* const* d_in, const int* in_sizes, int n_in,
                              void* d_out, int out_size, void* d_ws, size_t ws_size,
                              hipStream_t stream) {
  (void)in_sizes; (void)n_in; (void)out_size; (void)ws_size;
  const void* x    = d_in[0];
  const int* rules = (const int*)d_in[1];
  const void* q_si = d_in[2];  const void* q_so = d_in[3];
  const void* q_ri = d_in[4];  const void* q_ro = d_in[5];  const void* q_lg = d_in[6];
  const void* k_si = d_in[7];  const void* k_so = d_in[8];
  const void* k_ri = d_in[9];  const void* k_ro = d_in[10]; const void* k_lg = d_in[11];
  const void* v_si = d_in[12]; const void* v_so = d_in[13];
  const void* v_ri = d_in[14]; const void* v_ro = d_in[15]; const void* v_lg = d_in[16];
  const void* o_si = d_in[17]; const void* o_so = d_in[18];
  const void* o_ri = d_in[19]; const void* o_ro = d_in[20]; const void* o_lg = d_in[21];
  const void* rq   = d_in[22]; const void* rk   = d_in[23];

  char* ws = (char*)d_ws;
  const size_t MB = 1024*1024;
  float*          qb    = (float*)(ws);                     // 16 MB fp32 (also attn out, in-place)
  unsigned short* kb    = (unsigned short*)(ws + 16*MB);    // 8 MB bf16
  unsigned short* vb    = (unsigned short*)(ws + 24*MB);    // 8 MB bf16
  unsigned short* listb = (unsigned short*)(ws + 32*MB);    // 8 MB
  int*            cntb  = (int*)  (ws + 49*MB);             // 16 KB
  float*          Mt    = (float*)(ws + 49*MB + 16*1024);   // 16 KB
  float*          selt  = (float*)(ws + 49*MB + 32*1024);   // 16 KB
  int*            flag  = (int*)  (ws + 49*MB + 48*1024);

  detect_kernel<<<1, 64, 0, stream>>>((const unsigned short*)x, flag);
  precompute_kernel<<<1, 256, 0, stream>>>(rq, rk, q_lg, k_lg, v_lg, o_lg, Mt, selt, flag);

  AB_qkv_bf16<<<dim3(NGRP, 3), 256, 0, stream>>>(x, rules,
      q_si, q_ri, q_so, q_ro, k_si, k_ri, k_so, k_ro, v_si, v_ri, v_so, v_ro,
      selt, qb, kb, vb, flag);
  AB_qkv_f32 <<<dim3(NGRP, 3), 256, 0, stream>>>(x, rules,
      q_si, q_ri, q_so, q_ro, k_si, k_ri, k_so, k_ro, v_si, v_ri, v_so, v_ro,
      selt, qb, kb, vb, flag);
  mask_kernel<<<NTOK, 64, 0, stream>>>(rules, Mt, listb, cntb);
  attn_kernel<<<dim3(SS, BB, 4), 256, 0, stream>>>(qb, kb, vb, listb, cntb, qb);

  AB_o_bf16<<<NGRP, 256, 0, stream>>>(qb, rules, o_si, o_ri, o_so, o_ro, selt + 3*1024, d_out, flag);
  AB_o_f32 <<<NGRP, 256, 0, stream>>>(qb, rules, o_si, o_ri, o_so, o_ro, selt + 3*1024, d_out, flag);
}

// Round 11
// 339.036 us; speedup vs baseline: 1.0999x; 1.0999x over previous
//
#include <hip/hip_runtime.h>
#include <hip/hip_bf16.h>

#define D_MODEL 1024
#define N_HEADS 16
#define HEAD_DIM 64
#define NUM_RULES 64
#define RANK 8
#define SHARED_RANK 32
#define NUM_BLOCKS_ 16
#define BB 4
#define SS 1024
#define NTOK (BB*SS)
#define NGRP (NTOK/8)   // 512 token-groups of 8

__device__ __forceinline__ float bf2f(unsigned short u) {
  unsigned int i = ((unsigned int)u) << 16;
  float f;
  __builtin_memcpy(&f, &i, 4);
  return f;
}
__device__ __forceinline__ unsigned short f2bf(float f) {
  __hip_bfloat16 h = __float2bfloat16(f);
  unsigned short u;
  __builtin_memcpy(&u, &h, 2);
  return u;
}
__device__ __forceinline__ float u2f(unsigned int i) {
  float f;
  __builtin_memcpy(&f, &i, 4);
  return f;
}
template<bool BF>
__device__ __forceinline__ float ldw(const void* p, size_t i) {
  if (BF) return bf2f(((const unsigned short*)p)[i]);
  else    return ((const float*)p)[i];
}

// ---------------------------------------------------------------------------
// Dtype detection
// ---------------------------------------------------------------------------
__global__ void detect_kernel(const unsigned short* __restrict__ x, int* __restrict__ flag) {
  const int lane = threadIdx.x;  // 64
  int good = 0;
  for (int i = 0; i < 4; i++) {
    unsigned short u = x[lane*4 + i];
    int e = (u >> 7) & 0xFF;
    good += (e == 0 || (e >= 100 && e <= 145)) ? 1 : 0;
  }
  for (int off = 32; off; off >>= 1) good += __shfl_xor(good, off);
  if (lane == 0) flag[0] = (good >= 224) ? 1 : 0;
}

// ---------------------------------------------------------------------------
// Precompute: M[64][64] and sel[4][64][16]
// ---------------------------------------------------------------------------
template<bool BF>
__device__ __forceinline__ void precompute_body(
    const void* rq, const void* rk,
    const void* qlg, const void* klg, const void* vlg, const void* olg,
    float* __restrict__ M, float* __restrict__ sel)
{
  __shared__ float rqn[64][8], rkn[64][8];
  const int tid = threadIdx.x;  // 256
  if (tid < 64) {
    float v[8]; float s = 0.f;
    for (int i = 0; i < 8; i++) { v[i] = ldw<BF>(rq, tid*8+i); s += v[i]*v[i]; }
    float inv = 1.0f / fmaxf(sqrtf(s), 1e-12f);
    for (int i = 0; i < 8; i++) rqn[tid][i] = v[i]*inv;
  } else if (tid < 128) {
    int r = tid - 64;
    float v[8]; float s = 0.f;
    for (int i = 0; i < 8; i++) { v[i] = ldw<BF>(rk, r*8+i); s += v[i]*v[i]; }
    float inv = 1.0f / fmaxf(sqrtf(s), 1e-12f);
    for (int i = 0; i < 8; i++) rkn[r][i] = v[i]*inv;
  }
  __syncthreads();
  const float LN8 = 2.0794415416798357f;  // 1/tau = ln(8)
  for (int idx = tid; idx < 64*64; idx += 256) {
    int i = idx >> 6, j = idx & 63;
    float d = 0.f;
    for (int t = 0; t < 8; t++) d += rqn[i][t]*rkn[j][t];
    M[idx] = d * LN8;
  }
  const void* lgs[4] = {qlg, klg, vlg, olg};
  {
    int r = tid & 63;
    const void* lg = lgs[tid >> 6];
    float e[NUM_BLOCKS_]; float mx = -1e30f;
    for (int b = 0; b < NUM_BLOCKS_; b++) {
      e[b] = ldw<BF>(lg, r*NUM_BLOCKS_ + b) * 4.0f;
      mx = fmaxf(mx, e[b]);
    }
    float s = 0.f;
    for (int b = 0; b < NUM_BLOCKS_; b++) { e[b] = expf(e[b]-mx); s += e[b]; }
    float inv = 1.0f/s;
    for (int b = 0; b < NUM_BLOCKS_; b++) sel[tid*NUM_BLOCKS_+b] = e[b]*inv;
  }
}

__global__ void precompute_kernel(
    const void* rq, const void* rk,
    const void* qlg, const void* klg, const void* vlg, const void* olg,
    float* M, float* sel, const int* __restrict__ flag)
{
  if (*flag) precompute_body<true >(rq, rk, qlg, klg, vlg, olg, M, sel);
  else       precompute_body<false>(rq, rk, qlg, klg, vlg, olg, M, sel);
}

// ---------------------------------------------------------------------------
// Stage A: tt[n][32] = x[n]@si, hh[n][16][8] = per-rule lowrank inner.
// 8 tokens/block, 256 threads. ONE template instantiation per __global__.
// (Split A/B is deliberate: fusing them (R10) hit 256 VGPR + 64 MB spill;
//  the 15.6 MB ttg/hhg round-trip is far cheaper.)
// ---------------------------------------------------------------------------
template<bool IN_BF, bool W_BF>
__device__ __forceinline__ void stageA_body(
    const void* __restrict__ xin, const int* __restrict__ rules,
    const void* __restrict__ si, const void* __restrict__ ri,
    float* __restrict__ ttg, float* __restrict__ hhg, int yslot)
{
  const int g = blockIdx.x, n0 = g*8, tid = threadIdx.x;
  __shared__ float xs[8][D_MODEL];     // 32 KB
  __shared__ float tpart[8][32][9];    // pad 9: conflict-free reduce
  __shared__ int rl[8];

  #pragma unroll
  for (int t = 0; t < 8; t++) {
    float4 f;
    if (IN_BF) {
      ushort4 u = ((const ushort4*)((const unsigned short*)xin + (size_t)(n0+t)*D_MODEL))[tid];
      f.x = bf2f(u.x); f.y = bf2f(u.y); f.z = bf2f(u.z); f.w = bf2f(u.w);
    } else {
      f = ((const float4*)xin)[(size_t)(n0+t)*(D_MODEL/4) + tid];
    }
    *(float4*)&xs[t][tid*4] = f;
  }
  if (tid < 8) rl[tid] = rules[n0 + tid];
  __syncthreads();

  {
    const int c = tid >> 5, j = tid & 31;
    float p[8];
    #pragma unroll
    for (int t = 0; t < 8; t++) p[t] = 0.f;
    for (int d4 = 0; d4 < 32; d4++) {
      const int d = c*128 + d4*4;
      float w0 = ldw<W_BF>(si, (size_t)(d+0)*SHARED_RANK + j);
      float w1 = ldw<W_BF>(si, (size_t)(d+1)*SHARED_RANK + j);
      float w2 = ldw<W_BF>(si, (size_t)(d+2)*SHARED_RANK + j);
      float w3 = ldw<W_BF>(si, (size_t)(d+3)*SHARED_RANK + j);
      #pragma unroll
      for (int t = 0; t < 8; t++) {
        float4 xv = *(const float4*)&xs[t][d];   // broadcast across j-lanes
        p[t] += xv.x*w0 + xv.y*w1 + xv.z*w2 + xv.w*w3;
      }
    }
    #pragma unroll
    for (int t = 0; t < 8; t++) tpart[c][j][t] = p[t];
  }
  __syncthreads();

  {
    const int t = tid >> 5, j = tid & 31;
    float s = 0.f;
    #pragma unroll
    for (int c = 0; c < 8; c++) s += tpart[c][j][t];
    ttg[(size_t)(yslot*NGRP + g)*256 + j*8 + t] = s;
  }
  {
    const int t = tid >> 5, blk = (tid >> 1) & 15, r0 = (tid & 1)*4;
    const int rule = rl[t];
    float a0=0.f, a1=0.f, a2=0.f, a3=0.f;
    for (int k4 = 0; k4 < 16; k4++) {
      const int kk = ((k4 + blk) & 15) * 4;   // rotate: spreads LDS banks
      float4 xv = *(const float4*)&xs[t][blk*64 + kk];
      #pragma unroll
      for (int q = 0; q < 4; q++) {
        const int k = kk + q;
        float w0,w1,w2,w3;
        if (W_BF) {
          ushort4 u = *(const ushort4*)((const unsigned short*)ri + (size_t)rule*512 + (size_t)k*8 + r0);
          w0=bf2f(u.x); w1=bf2f(u.y); w2=bf2f(u.z); w3=bf2f(u.w);
        } else {
          float4 u = *(const float4*)((const float*)ri + (size_t)rule*512 + (size_t)k*8 + r0);
          w0=u.x; w1=u.y; w2=u.z; w3=u.w;
        }
        float xq = (q==0)?xv.x:((q==1)?xv.y:((q==2)?xv.z:xv.w));
        a0 += xq*w0; a1 += xq*w1; a2 += xq*w2; a3 += xq*w3;
      }
    }
    float4 hv; hv.x=a0; hv.y=a1; hv.z=a2; hv.w=a3;
    *(float4*)&hhg[((size_t)yslot*NTOK + n0 + t)*128 + blk*8 + r0] = hv;
  }
}

__global__ __launch_bounds__(256) void A_qkv_bf16(
    const void* x, const int* rules,
    const void* qsi, const void* qri, const void* ksi, const void* kri,
    const void* vsi, const void* vri,
    float* ttg, float* hhg, const int* __restrict__ flag)
{
  if (!*flag) return;
  const int y = blockIdx.y;
  const void* si = (y==0)?qsi:((y==1)?ksi:vsi);
  const void* ri = (y==0)?qri:((y==1)?kri:vri);
  stageA_body<true,true>(x, rules, si, ri, ttg, hhg, y);
}

__global__ __launch_bounds__(256) void A_qkv_f32(
    const void* x, const int* rules,
    const void* qsi, const void* qri, const void* ksi, const void* kri,
    const void* vsi, const void* vri,
    float* ttg, float* hhg, const int* __restrict__ flag)
{
  if (*flag) return;
  const int y = blockIdx.y;
  const void* si = (y==0)?qsi:((y==1)?ksi:vsi);
  const void* ri = (y==0)?qri:((y==1)?kri:vri);
  stageA_body<false,false>(x, rules, si, ri, ttg, hhg, y);
}

// o-projection stage A with bf16 weights but fp32 input (attn output)
__global__ __launch_bounds__(256) void A_o_bf16(
    const void* ain, const int* rules, const void* osi, const void* ori,
    float* ttg, float* hhg, const int* __restrict__ flag)
{
  if (!*flag) return;
  stageA_body<false,true>(ain, rules, osi, ori, ttg, hhg, 0);
}

// ---------------------------------------------------------------------------
// Stage B: thread = 4 consecutive channels (ch0 = tid*4).
// so loads coalesced float4/ushort4; tt/hh via LDS broadcast; ro/sel from
// global (hot in L1).
// ---------------------------------------------------------------------------
template<bool W_BF>
__device__ __forceinline__ void stageB_body(
    const float* __restrict__ ttg, const float* __restrict__ hhg,
    const int* __restrict__ rules,
    const void* __restrict__ so, const void* __restrict__ ro,
    const float* __restrict__ sel, void* __restrict__ out,
    int yslot, int do_rope, int out_bf)
{
  const int g = blockIdx.x, n0 = g*8, tid = threadIdx.x;
  __shared__ float tt_lds[32][9];    // [j][t], pad 9
  __shared__ float hh_lds[8][132];   // [t][blk*8+r], pad 132
  __shared__ int rl[8];

  { const int j = tid >> 3, t = tid & 7;
    tt_lds[j][t] = ttg[(size_t)(yslot*NGRP + g)*256 + tid]; }
  { float4 hv = *(const float4*)&hhg[((size_t)yslot*NTOK + n0)*128 + tid*4];
    const int t = tid >> 5, c = (tid*4) & 127;
    *(float4*)&hh_lds[t][c] = hv; }
  if (tid < 8) rl[tid] = rules[n0 + tid];
  __syncthreads();

  const int ch0 = tid*4;
  float a0[8], a1[8], a2[8], a3[8];
  #pragma unroll
  for (int t = 0; t < 8; t++) { a0[t]=0.f; a1[t]=0.f; a2[t]=0.f; a3[t]=0.f; }

  for (int j = 0; j < 32; j++) {
    float w0, w1, w2, w3;
    if (W_BF) {
      ushort4 u = *(const ushort4*)((const unsigned short*)so + (size_t)j*D_MODEL + ch0);
      w0=bf2f(u.x); w1=bf2f(u.y); w2=bf2f(u.z); w3=bf2f(u.w);
    } else {
      float4 u = *(const float4*)((const float*)so + (size_t)j*D_MODEL + ch0);
      w0=u.x; w1=u.y; w2=u.z; w3=u.w;
    }
    #pragma unroll
    for (int t = 0; t < 8; t++) {
      float tv = tt_lds[j][t];         // LDS broadcast
      a0[t] += tv*w0; a1[t] += tv*w1; a2[t] += tv*w2; a3[t] += tv*w3;
    }
  }

  const int blk = ch0 >> 6, tc = ch0 & 63;
  float inv0 = 0.f, inv1 = 0.f;
  if (do_rope) {
    inv0 = expf(-(float)tc     * (9.210340371976184f/64.0f));   // 2*i0 == tc
    inv1 = expf(-(float)(tc+2) * (9.210340371976184f/64.0f));
  }
  #pragma unroll
  for (int t = 0; t < 8; t++) {
    const int rule = rl[t];
    float b0=0.f, b1=0.f, b2=0.f, b3=0.f;
    #pragma unroll
    for (int r = 0; r < 8; r++) {
      float w0,w1,w2,w3;
      if (W_BF) {
        ushort4 u = *(const ushort4*)((const unsigned short*)ro + (size_t)rule*512 + r*64 + tc);
        w0=bf2f(u.x); w1=bf2f(u.y); w2=bf2f(u.z); w3=bf2f(u.w);
      } else {
        float4 u = *(const float4*)((const float*)ro + (size_t)rule*512 + r*64 + tc);
        w0=u.x; w1=u.y; w2=u.z; w3=u.w;
      }
      float hv = hh_lds[t][blk*8 + r];
      b0 += hv*w0; b1 += hv*w1; b2 += hv*w2; b3 += hv*w3;
    }
    float sb = sel[rule*NUM_BLOCKS_ + blk];
    float e0 = a0[t] + b0*sb, o0 = a1[t] + b1*sb;
    float e1 = a2[t] + b2*sb, o1 = a3[t] + b3*sb;
    const int n = n0 + t;
    if (do_rope) {
      float spos = (float)(n & (SS-1));
      float sn0, cs0, sn1, cs1;
      sincosf(spos*inv0, &sn0, &cs0);
      sincosf(spos*inv1, &sn1, &cs1);
      float u0 = e0*cs0 - o0*sn0; o0 = o0*cs0 + e0*sn0; e0 = u0;
      float u1 = e1*cs1 - o1*sn1; o1 = o1*cs1 + e1*sn1; e1 = u1;
    }
    if (out_bf) {
      ushort4 uv; uv.x=f2bf(e0); uv.y=f2bf(o0); uv.z=f2bf(e1); uv.w=f2bf(o1);
      *(ushort4*)((unsigned short*)out + (size_t)n*D_MODEL + ch0) = uv;
    } else {
      float4 fv; fv.x=e0; fv.y=o0; fv.z=e1; fv.w=o1;
      *(float4*)((float*)out + (size_t)n*D_MODEL + ch0) = fv;
    }
  }
}

__global__ __launch_bounds__(256) void B_qkv_bf16(
    const float* ttg, const float* hhg, const int* rules,
    const void* qso, const void* qro, const void* kso, const void* kro,
    const void* vso, const void* vro,
    const float* sel, float* qb, unsigned short* kb, unsigned short* vb,
    const int* __restrict__ flag)
{
  if (!*flag) return;
  const int y = blockIdx.y;
  const void* so = (y==0)?qso:((y==1)?kso:vso);
  const void* ro = (y==0)?qro:((y==1)?kro:vro);
  void* out = (y==0)?(void*)qb:((y==1)?(void*)kb:(void*)vb);
  stageB_body<true>(ttg, hhg, rules, so, ro, sel + y*1024, out, y, (y<2)?1:0, (y>=1)?1:0);
}

__global__ __launch_bounds__(256) void B_qkv_f32(
    const float* ttg, const float* hhg, const int* rules,
    const void* qso, const void* qro, const void* kso, const void* kro,
    const void* vso, const void* vro,
    const float* sel, float* qb, unsigned short* kb, unsigned short* vb,
    const int* __restrict__ flag)
{
  if (*flag) return;
  const int y = blockIdx.y;
  const void* so = (y==0)?qso:((y==1)?kso:vso);
  const void* ro = (y==0)?qro:((y==1)?kro:vro);
  void* out = (y==0)?(void*)qb:((y==1)?(void*)kb:(void*)vb);
  stageB_body<false>(ttg, hhg, rules, so, ro, sel + y*1024, out, y, (y<2)?1:0, (y>=1)?1:0);
}

__global__ __launch_bounds__(256) void B_o_bf16(
    const float* ttg, const float* hhg, const int* rules,
    const void* oso, const void* oro, const float* sel, void* out,
    const int* __restrict__ flag)
{
  if (!*flag) return;
  stageB_body<true>(ttg, hhg, rules, oso, oro, sel, out, 0, 0, 1);
}

__global__ __launch_bounds__(256) void B_o_f32(
    const float* ttg, const float* hhg, const int* rules,
    const void* oso, const void* oro, const float* sel, void* out,
    const int* __restrict__ flag)
{
  if (*flag) return;
  stageB_body<false>(ttg, hhg, rules, oso, oro, sel, out, 0, 0, 0);
}

// ---------------------------------------------------------------------------
// Router mask — one 64-thread wave per (b,q); LDS-atomic histogram with
// barrier before read.
// ---------------------------------------------------------------------------
__global__ __launch_bounds__(64) void mask_kernel(
    const int* __restrict__ rules, const float* __restrict__ M,
    unsigned short* __restrict__ list, int* __restrict__ cntout)
{
  const int bid = blockIdx.x;              // b*1024 + qi
  const int b = bid >> 10, qi = bid & 1023;
  const int lane = threadIdx.x;
  __shared__ int rrow[SS];
  __shared__ float val[64];
  __shared__ int cnth[64];
  for (int i = lane; i < SS/4; i += 64)
    ((int4*)rrow)[i] = ((const int4*)(rules + b*SS))[i];
  cnth[lane] = 0;
  __syncthreads();                          // rrow + cnth=0 visible
  for (int k = lane; k <= qi; k += 64) atomicAdd(&cnth[rrow[k]], 1);
  const int qrule = rrow[qi];
  const float myv = M[qrule*64 + lane];
  val[lane] = myv;
  __syncthreads();                          // histogram + val visible
  const int c = cnth[lane];
  int A = 0;
  for (int r = 0; r < 64; r++) {
    int cr = __shfl(c, r);
    A += (val[r] > myv) ? cr : 0;
  }
  unsigned long long allowed = __ballot(A < 32);
  unsigned short* lp = list + (size_t)bid*SS;
  int pos = 0;
  const unsigned long long lmask = (1ULL << lane) - 1ULL;
  for (int k0 = 0; k0 <= qi; k0 += 64) {
    int k = k0 + lane;
    int kc = (k <= qi) ? k : qi;
    bool ok = (k <= qi) && (((allowed >> rrow[kc]) & 1ULL) != 0ULL);
    unsigned long long bal = __ballot(ok);
    if (ok) lp[pos + __popcll(bal & lmask)] = (unsigned short)k;
    pos += __popcll(bal);
  }
  if (lane == 0) cntout[bid] = pos;
}

// ---------------------------------------------------------------------------
// Sparse attention: block = (b, q, head-group of 4); 4 waves, one head each.
// keyl padded to 64-multiple -> uniform PV loop, no clamp, all shfl lanes
// active (R8 lesson). Dword-level bf16 unpack.
// ---------------------------------------------------------------------------
__global__ __launch_bounds__(256) void attn_kernel(
    const float* __restrict__ qb,
    const unsigned short* __restrict__ kb, const unsigned short* __restrict__ vb,
    const unsigned short* __restrict__ list, const int* __restrict__ cnt,
    float* __restrict__ outb)
{
  const int qi = blockIdx.x, b = blockIdx.y, hg = blockIdx.z;
  const int tid = threadIdx.x, lane = tid & 63, w = tid >> 6;
  const int nq = b*SS + qi;
  const int h = hg*4 + w;
  __shared__ unsigned short keyl[SS + 64];
  __shared__ float qs[4][64];
  const int total = cnt[nq];
  const int padded = (total + 63) & ~63;
  const unsigned short* lp = list + (size_t)nq*SS;
  for (int i = tid; i < total; i += 256) keyl[i] = lp[i];
  if (total < padded) {
    unsigned short k0 = lp[0];
    for (int i = total + tid; i < padded; i += 256) keyl[i] = k0;
  }
  qs[w][lane] = qb[(size_t)nq*D_MODEL + h*HEAD_DIM + lane] * 0.125f;
  __syncthreads();

  const unsigned short* kbase = kb + (size_t)b*SS*D_MODEL + h*HEAD_DIM;
  const unsigned short* vbase = vb + (size_t)b*SS*D_MODEL + h*HEAD_DIM;
  const int g = lane >> 4, d4 = lane & 15;
  float4 acc = {0.f,0.f,0.f,0.f};
  float m = -1e30f, l = 0.f;
  for (int c0 = 0; c0 < total; c0 += 64) {
    int nc = total - c0; if (nc > 64) nc = 64;
    float s = -1e30f;
    if (lane < nc) {
      int key = keyl[c0 + lane];
      const uint2* kr = (const uint2*)(kbase + (size_t)key*D_MODEL);
      float sum = 0.f;
      #pragma unroll
      for (int t = 0; t < 16; t++) {
        uint2 kw = kr[t];
        float4 qv = *(const float4*)&qs[w][4*t];  // LDS broadcast
        sum += qv.x*u2f(kw.x << 16) + qv.y*u2f(kw.x & 0xffff0000u)
             + qv.z*u2f(kw.y << 16) + qv.w*u2f(kw.y & 0xffff0000u);
      }
      s = sum;
    }
    float cm = s;
    #pragma unroll
    for (int off = 32; off; off >>= 1) cm = fmaxf(cm, __shfl_xor(cm, off));
    float newm = fmaxf(m, cm);
    float alpha = expf(m - newm);
    float ww = (lane < nc) ? expf(s - newm) : 0.f;
    float lsum = ww;
    #pragma unroll
    for (int off = 32; off; off >>= 1) lsum += __shfl_xor(lsum, off);
    l = l*alpha + lsum;
    m = newm;
    acc.x *= alpha; acc.y *= alpha; acc.z *= alpha; acc.w *= alpha;
    #pragma unroll 4
    for (int it = 0; it < 16; it++) {
      int i = g + it*4;
      float wi = __shfl(ww, i);
      int key = keyl[c0 + i];
      uint2 vw = *(const uint2*)(vbase + (size_t)key*D_MODEL + d4*4);
      acc.x += wi*u2f(vw.x << 16); acc.y += wi*u2f(vw.x & 0xffff0000u);
      acc.z += wi*u2f(vw.y << 16); acc.w += wi*u2f(vw.y & 0xffff0000u);
    }
  }
  acc.x += __shfl_xor(acc.x, 16); acc.y += __shfl_xor(acc.y, 16);
  acc.z += __shfl_xor(acc.z, 16); acc.w += __shfl_xor(acc.w, 16);
  acc.x += __shfl_xor(acc.x, 32); acc.y += __shfl_xor(acc.y, 32);
  acc.z += __shfl_xor(acc.z, 32); acc.w += __shfl_xor(acc.w, 32);
  if (lane < 16) {
    float invl = 1.0f / l;
    float4 o;
    o.x = acc.x*invl; o.y = acc.y*invl; o.z = acc.z*invl; o.w = acc.w*invl;
    *(float4*)(outb + (size_t)nq*D_MODEL + h*HEAD_DIM + d4*4) = o;
  }
}

// ---------------------------------------------------------------------------
extern "C" void kernel_launch(void* const* d_in, const int* in_sizes, int n_in,
                              void* d_out, int out_size, void* d_ws, size_t ws_size,
                              hipStream_t stream) {
  (void)in_sizes; (void)n_in; (void)out_size; (void)ws_size;
  const void* x    = d_in[0];
  const int* rules = (const int*)d_in[1];
  const void* q_si = d_in[2];  const void* q_so = d_in[3];
  const void* q_ri = d_in[4];  const void* q_ro = d_in[5];  const void* q_lg = d_in[6];
  const void* k_si = d_in[7];  const void* k_so = d_in[8];
  const void* k_ri = d_in[9];  const void* k_ro = d_in[10]; const void* k_lg = d_in[11];
  const void* v_si = d_in[12]; const void* v_so = d_in[13];
  const void* v_ri = d_in[14]; const void* v_ro = d_in[15]; const void* v_lg = d_in[16];
  const void* o_si = d_in[17]; const void* o_so = d_in[18];
  const void* o_ri = d_in[19]; const void* o_ro = d_in[20]; const void* o_lg = d_in[21];
  const void* rq   = d_in[22]; const void* rk   = d_in[23];

  char* ws = (char*)d_ws;
  const size_t MB = 1024*1024;
  float*          qb    = (float*)(ws);                     // 16 MB fp32 (also attn out, in-place)
  unsigned short* kb    = (unsigned short*)(ws + 16*MB);    // 8 MB bf16
  unsigned short* vb    = (unsigned short*)(ws + 24*MB);    // 8 MB bf16
  unsigned short* listb = (unsigned short*)(ws + 32*MB);    // 8 MB
  float*          ttg   = (float*)(ws + 40*MB);             // 1.5 MB
  float*          hhg   = (float*)(ws + 42*MB);             // 6.3 MB
  int*            cntb  = (int*)  (ws + 49*MB);             // 16 KB
  float*          Mt    = (float*)(ws + 49*MB + 16*1024);   // 16 KB
  float*          selt  = (float*)(ws + 49*MB + 32*1024);   // 16 KB
  int*            flag  = (int*)  (ws + 49*MB + 48*1024);

  detect_kernel<<<1, 64, 0, stream>>>((const unsigned short*)x, flag);
  precompute_kernel<<<1, 256, 0, stream>>>(rq, rk, q_lg, k_lg, v_lg, o_lg, Mt, selt, flag);

  A_qkv_bf16<<<dim3(NGRP, 3), 256, 0, stream>>>(x, rules, q_si, q_ri, k_si, k_ri, v_si, v_ri, ttg, hhg, flag);
  A_qkv_f32 <<<dim3(NGRP, 3), 256, 0, stream>>>(x, rules, q_si, q_ri, k_si, k_ri, v_si, v_ri, ttg, hhg, flag);
  B_qkv_bf16<<<dim3(NGRP, 3), 256, 0, stream>>>(ttg, hhg, rules, q_so, q_ro, k_so, k_ro, v_so, v_ro,
                                                selt, qb, kb, vb, flag);
  B_qkv_f32 <<<dim3(NGRP, 3), 256, 0, stream>>>(ttg, hhg, rules, q_so, q_ro, k_so, k_ro, v_so, v_ro,
                                                selt, qb, kb, vb, flag);
  mask_kernel<<<NTOK, 64, 0, stream>>>(rules, Mt, listb, cntb);
  attn_kernel<<<dim3(SS, BB, 4), 256, 0, stream>>>(qb, kb, vb, listb, cntb, qb);

  // o-projection: stage A (fp32 input from attn), then stage B to d_out
  A_o_bf16<<<dim3(NGRP, 1), 256, 0, stream>>>(qb, rules, o_si, o_ri, ttg, hhg, flag);
  A_qkv_f32<<<dim3(NGRP, 1), 256, 0, stream>>>(qb, rules, o_si, o_ri, o_si, o_ri, o_si, o_ri, ttg, hhg, flag);
  B_o_bf16<<<NGRP, 256, 0, stream>>>(ttg, hhg, rules, o_so, o_ro, selt + 3*1024, d_out, flag);
  B_o_f32 <<<NGRP, 256, 0, stream>>>(ttg, hhg, rules, o_so, o_ro, selt + 3*1024, d_out, flag);
}

// Round 12
// 331.533 us; speedup vs baseline: 1.1248x; 1.0226x over previous
//
#include <hip/hip_runtime.h>
#include <hip/hip_bf16.h>

#define D_MODEL 1024
#define N_HEADS 16
#define HEAD_DIM 64
#define NUM_RULES 64
#define RANK 8
#define SHARED_RANK 32
#define NUM_BLOCKS_ 16
#define BB 4
#define SS 1024
#define NTOK (BB*SS)
#define NGRP (NTOK/8)   // 512 token-groups of 8

__device__ __forceinline__ float bf2f(unsigned short u) {
  unsigned int i = ((unsigned int)u) << 16;
  float f;
  __builtin_memcpy(&f, &i, 4);
  return f;
}
__device__ __forceinline__ unsigned short f2bf(float f) {
  __hip_bfloat16 h = __float2bfloat16(f);
  unsigned short u;
  __builtin_memcpy(&u, &h, 2);
  return u;
}
__device__ __forceinline__ float u2f(unsigned int i) {
  float f;
  __builtin_memcpy(&f, &i, 4);
  return f;
}
template<bool BF>
__device__ __forceinline__ float ldw(const void* p, size_t i) {
  if (BF) return bf2f(((const unsigned short*)p)[i]);
  else    return ((const float*)p)[i];
}

// ---------------------------------------------------------------------------
// Dtype detection
// ---------------------------------------------------------------------------
__global__ void detect_kernel(const unsigned short* __restrict__ x, int* __restrict__ flag) {
  const int lane = threadIdx.x;  // 64
  int good = 0;
  for (int i = 0; i < 4; i++) {
    unsigned short u = x[lane*4 + i];
    int e = (u >> 7) & 0xFF;
    good += (e == 0 || (e >= 100 && e <= 145)) ? 1 : 0;
  }
  for (int off = 32; off; off >>= 1) good += __shfl_xor(good, off);
  if (lane == 0) flag[0] = (good >= 224) ? 1 : 0;
}

// ---------------------------------------------------------------------------
// Precompute: M[64][64] and sel[4][64][16]
// ---------------------------------------------------------------------------
template<bool BF>
__device__ __forceinline__ void precompute_body(
    const void* rq, const void* rk,
    const void* qlg, const void* klg, const void* vlg, const void* olg,
    float* __restrict__ M, float* __restrict__ sel)
{
  __shared__ float rqn[64][8], rkn[64][8];
  const int tid = threadIdx.x;  // 256
  if (tid < 64) {
    float v[8]; float s = 0.f;
    for (int i = 0; i < 8; i++) { v[i] = ldw<BF>(rq, tid*8+i); s += v[i]*v[i]; }
    float inv = 1.0f / fmaxf(sqrtf(s), 1e-12f);
    for (int i = 0; i < 8; i++) rqn[tid][i] = v[i]*inv;
  } else if (tid < 128) {
    int r = tid - 64;
    float v[8]; float s = 0.f;
    for (int i = 0; i < 8; i++) { v[i] = ldw<BF>(rk, r*8+i); s += v[i]*v[i]; }
    float inv = 1.0f / fmaxf(sqrtf(s), 1e-12f);
    for (int i = 0; i < 8; i++) rkn[r][i] = v[i]*inv;
  }
  __syncthreads();
  const float LN8 = 2.0794415416798357f;  // 1/tau = ln(8)
  for (int idx = tid; idx < 64*64; idx += 256) {
    int i = idx >> 6, j = idx & 63;
    float d = 0.f;
    for (int t = 0; t < 8; t++) d += rqn[i][t]*rkn[j][t];
    M[idx] = d * LN8;
  }
  const void* lgs[4] = {qlg, klg, vlg, olg};
  {
    int r = tid & 63;
    const void* lg = lgs[tid >> 6];
    float e[NUM_BLOCKS_]; float mx = -1e30f;
    for (int b = 0; b < NUM_BLOCKS_; b++) {
      e[b] = ldw<BF>(lg, r*NUM_BLOCKS_ + b) * 4.0f;
      mx = fmaxf(mx, e[b]);
    }
    float s = 0.f;
    for (int b = 0; b < NUM_BLOCKS_; b++) { e[b] = expf(e[b]-mx); s += e[b]; }
    float inv = 1.0f/s;
    for (int b = 0; b < NUM_BLOCKS_; b++) sel[tid*NUM_BLOCKS_+b] = e[b]*inv;
  }
}

__global__ void precompute_kernel(
    const void* rq, const void* rk,
    const void* qlg, const void* klg, const void* vlg, const void* olg,
    float* M, float* sel, const int* __restrict__ flag)
{
  if (*flag) precompute_body<true >(rq, rk, qlg, klg, vlg, olg, M, sel);
  else       precompute_body<false>(rq, rk, qlg, klg, vlg, olg, M, sel);
}

// ---------------------------------------------------------------------------
// Stage A: tt[n][32] = x[n]@si, hh[n][16][8] = per-rule lowrank inner.
// 8 tokens/block, 256 threads. ONE template instantiation per __global__.
// (Split A/B deliberate: fusing (R10) hit 256 VGPR + 64 MB spill.)
// #pragma unroll 4 on the weight loop: full unroll hoisted 128 load-dest
// VGPRs (R11: 208 VGPR, 10% occupancy on B; same pathology here).
// ---------------------------------------------------------------------------
template<bool IN_BF, bool W_BF>
__device__ __forceinline__ void stageA_body(
    const void* __restrict__ xin, const int* __restrict__ rules,
    const void* __restrict__ si, const void* __restrict__ ri,
    float* __restrict__ ttg, float* __restrict__ hhg, int yslot)
{
  const int g = blockIdx.x, n0 = g*8, tid = threadIdx.x;
  __shared__ float xs[8][D_MODEL];     // 32 KB
  __shared__ float tpart[8][32][9];    // pad 9: conflict-free reduce
  __shared__ int rl[8];

  #pragma unroll
  for (int t = 0; t < 8; t++) {
    float4 f;
    if (IN_BF) {
      ushort4 u = ((const ushort4*)((const unsigned short*)xin + (size_t)(n0+t)*D_MODEL))[tid];
      f.x = bf2f(u.x); f.y = bf2f(u.y); f.z = bf2f(u.z); f.w = bf2f(u.w);
    } else {
      f = ((const float4*)xin)[(size_t)(n0+t)*(D_MODEL/4) + tid];
    }
    *(float4*)&xs[t][tid*4] = f;
  }
  if (tid < 8) rl[tid] = rules[n0 + tid];
  __syncthreads();

  {
    const int c = tid >> 5, j = tid & 31;
    float p[8];
    #pragma unroll
    for (int t = 0; t < 8; t++) p[t] = 0.f;
    #pragma unroll 4
    for (int d4 = 0; d4 < 32; d4++) {
      const int d = c*128 + d4*4;
      float w0 = ldw<W_BF>(si, (size_t)(d+0)*SHARED_RANK + j);
      float w1 = ldw<W_BF>(si, (size_t)(d+1)*SHARED_RANK + j);
      float w2 = ldw<W_BF>(si, (size_t)(d+2)*SHARED_RANK + j);
      float w3 = ldw<W_BF>(si, (size_t)(d+3)*SHARED_RANK + j);
      #pragma unroll
      for (int t = 0; t < 8; t++) {
        float4 xv = *(const float4*)&xs[t][d];   // broadcast across j-lanes
        p[t] += xv.x*w0 + xv.y*w1 + xv.z*w2 + xv.w*w3;
      }
    }
    #pragma unroll
    for (int t = 0; t < 8; t++) tpart[c][j][t] = p[t];
  }
  __syncthreads();

  {
    const int t = tid >> 5, j = tid & 31;
    float s = 0.f;
    #pragma unroll
    for (int c = 0; c < 8; c++) s += tpart[c][j][t];
    ttg[(size_t)(yslot*NGRP + g)*256 + j*8 + t] = s;
  }
  {
    const int t = tid >> 5, blk = (tid >> 1) & 15, r0 = (tid & 1)*4;
    const int rule = rl[t];
    float a0=0.f, a1=0.f, a2=0.f, a3=0.f;
    #pragma unroll 4
    for (int k4 = 0; k4 < 16; k4++) {
      const int kk = ((k4 + blk) & 15) * 4;   // rotate: spreads LDS banks
      float4 xv = *(const float4*)&xs[t][blk*64 + kk];
      #pragma unroll
      for (int q = 0; q < 4; q++) {
        const int k = kk + q;
        float w0,w1,w2,w3;
        if (W_BF) {
          ushort4 u = *(const ushort4*)((const unsigned short*)ri + (size_t)rule*512 + (size_t)k*8 + r0);
          w0=bf2f(u.x); w1=bf2f(u.y); w2=bf2f(u.z); w3=bf2f(u.w);
        } else {
          float4 u = *(const float4*)((const float*)ri + (size_t)rule*512 + (size_t)k*8 + r0);
          w0=u.x; w1=u.y; w2=u.z; w3=u.w;
        }
        float xq = (q==0)?xv.x:((q==1)?xv.y:((q==2)?xv.z:xv.w));
        a0 += xq*w0; a1 += xq*w1; a2 += xq*w2; a3 += xq*w3;
      }
    }
    float4 hv; hv.x=a0; hv.y=a1; hv.z=a2; hv.w=a3;
    *(float4*)&hhg[((size_t)yslot*NTOK + n0 + t)*128 + blk*8 + r0] = hv;
  }
}

__global__ __launch_bounds__(256) void A_qkv_bf16(
    const void* x, const int* rules,
    const void* qsi, const void* qri, const void* ksi, const void* kri,
    const void* vsi, const void* vri,
    float* ttg, float* hhg, const int* __restrict__ flag)
{
  if (!*flag) return;
  const int y = blockIdx.y;
  const void* si = (y==0)?qsi:((y==1)?ksi:vsi);
  const void* ri = (y==0)?qri:((y==1)?kri:vri);
  stageA_body<true,true>(x, rules, si, ri, ttg, hhg, y);
}

__global__ __launch_bounds__(256) void A_qkv_f32(
    const void* x, const int* rules,
    const void* qsi, const void* qri, const void* ksi, const void* kri,
    const void* vsi, const void* vri,
    float* ttg, float* hhg, const int* __restrict__ flag)
{
  if (*flag) return;
  const int y = blockIdx.y;
  const void* si = (y==0)?qsi:((y==1)?ksi:vsi);
  const void* ri = (y==0)?qri:((y==1)?kri:vri);
  stageA_body<false,false>(x, rules, si, ri, ttg, hhg, y);
}

// o-projection stage A with bf16 weights but fp32 input (attn output)
__global__ __launch_bounds__(256) void A_o_bf16(
    const void* ain, const int* rules, const void* osi, const void* ori,
    float* ttg, float* hhg, const int* __restrict__ flag)
{
  if (!*flag) return;
  stageA_body<false,true>(ain, rules, osi, ori, ttg, hhg, 0);
}

// ---------------------------------------------------------------------------
// Stage B: thread = 4 consecutive channels (ch0 = tid*4).
// #pragma unroll 4 on j-loop: R11 counters showed full unroll hoisting all
// 32 weight loads -> 208 VGPR, 10.6% occupancy, 16% VALUBusy. Capping the
// unroll keeps ~4 loads in flight (enough ILP) and frees ~128 VGPRs.
// ---------------------------------------------------------------------------
template<bool W_BF>
__device__ __forceinline__ void stageB_body(
    const float* __restrict__ ttg, const float* __restrict__ hhg,
    const int* __restrict__ rules,
    const void* __restrict__ so, const void* __restrict__ ro,
    const float* __restrict__ sel, void* __restrict__ out,
    int yslot, int do_rope, int out_bf)
{
  const int g = blockIdx.x, n0 = g*8, tid = threadIdx.x;
  __shared__ float tt_lds[32][9];    // [j][t], pad 9
  __shared__ float hh_lds[8][132];   // [t][blk*8+r], pad 132
  __shared__ int rl[8];

  { const int j = tid >> 3, t = tid & 7;
    tt_lds[j][t] = ttg[(size_t)(yslot*NGRP + g)*256 + tid]; }
  { float4 hv = *(const float4*)&hhg[((size_t)yslot*NTOK + n0)*128 + tid*4];
    const int t = tid >> 5, c = (tid*4) & 127;
    *(float4*)&hh_lds[t][c] = hv; }
  if (tid < 8) rl[tid] = rules[n0 + tid];
  __syncthreads();

  const int ch0 = tid*4;
  float a0[8], a1[8], a2[8], a3[8];
  #pragma unroll
  for (int t = 0; t < 8; t++) { a0[t]=0.f; a1[t]=0.f; a2[t]=0.f; a3[t]=0.f; }

  #pragma unroll 4
  for (int j = 0; j < 32; j++) {
    float w0, w1, w2, w3;
    if (W_BF) {
      ushort4 u = *(const ushort4*)((const unsigned short*)so + (size_t)j*D_MODEL + ch0);
      w0=bf2f(u.x); w1=bf2f(u.y); w2=bf2f(u.z); w3=bf2f(u.w);
    } else {
      float4 u = *(const float4*)((const float*)so + (size_t)j*D_MODEL + ch0);
      w0=u.x; w1=u.y; w2=u.z; w3=u.w;
    }
    #pragma unroll
    for (int t = 0; t < 8; t++) {
      float tv = tt_lds[j][t];         // LDS broadcast
      a0[t] += tv*w0; a1[t] += tv*w1; a2[t] += tv*w2; a3[t] += tv*w3;
    }
  }

  const int blk = ch0 >> 6, tc = ch0 & 63;
  float inv0 = 0.f, inv1 = 0.f;
  if (do_rope) {
    inv0 = expf(-(float)tc     * (9.210340371976184f/64.0f));   // 2*i0 == tc
    inv1 = expf(-(float)(tc+2) * (9.210340371976184f/64.0f));
  }
  #pragma unroll 2
  for (int t = 0; t < 8; t++) {
    const int rule = rl[t];
    float b0=0.f, b1=0.f, b2=0.f, b3=0.f;
    #pragma unroll
    for (int r = 0; r < 8; r++) {
      float w0,w1,w2,w3;
      if (W_BF) {
        ushort4 u = *(const ushort4*)((const unsigned short*)ro + (size_t)rule*512 + r*64 + tc);
        w0=bf2f(u.x); w1=bf2f(u.y); w2=bf2f(u.z); w3=bf2f(u.w);
      } else {
        float4 u = *(const float4*)((const float*)ro + (size_t)rule*512 + r*64 + tc);
        w0=u.x; w1=u.y; w2=u.z; w3=u.w;
      }
      float hv = hh_lds[t][blk*8 + r];
      b0 += hv*w0; b1 += hv*w1; b2 += hv*w2; b3 += hv*w3;
    }
    float sb = sel[rule*NUM_BLOCKS_ + blk];
    float e0 = a0[t] + b0*sb, o0 = a1[t] + b1*sb;
    float e1 = a2[t] + b2*sb, o1 = a3[t] + b3*sb;
    const int n = n0 + t;
    if (do_rope) {
      float spos = (float)(n & (SS-1));
      float sn0, cs0, sn1, cs1;
      sincosf(spos*inv0, &sn0, &cs0);
      sincosf(spos*inv1, &sn1, &cs1);
      float u0 = e0*cs0 - o0*sn0; o0 = o0*cs0 + e0*sn0; e0 = u0;
      float u1 = e1*cs1 - o1*sn1; o1 = o1*cs1 + e1*sn1; e1 = u1;
    }
    if (out_bf) {
      ushort4 uv; uv.x=f2bf(e0); uv.y=f2bf(o0); uv.z=f2bf(e1); uv.w=f2bf(o1);
      *(ushort4*)((unsigned short*)out + (size_t)n*D_MODEL + ch0) = uv;
    } else {
      float4 fv; fv.x=e0; fv.y=o0; fv.z=e1; fv.w=o1;
      *(float4*)((float*)out + (size_t)n*D_MODEL + ch0) = fv;
    }
  }
}

__global__ __launch_bounds__(256) void B_qkv_bf16(
    const float* ttg, const float* hhg, const int* rules,
    const void* qso, const void* qro, const void* kso, const void* kro,
    const void* vso, const void* vro,
    const float* sel, float* qb, unsigned short* kb, unsigned short* vb,
    const int* __restrict__ flag)
{
  if (!*flag) return;
  const int y = blockIdx.y;
  const void* so = (y==0)?qso:((y==1)?kso:vso);
  const void* ro = (y==0)?qro:((y==1)?kro:vro);
  void* out = (y==0)?(void*)qb:((y==1)?(void*)kb:(void*)vb);
  stageB_body<true>(ttg, hhg, rules, so, ro, sel + y*1024, out, y, (y<2)?1:0, (y>=1)?1:0);
}

__global__ __launch_bounds__(256) void B_qkv_f32(
    const float* ttg, const float* hhg, const int* rules,
    const void* qso, const void* qro, const void* kso, const void* kro,
    const void* vso, const void* vro,
    const float* sel, float* qb, unsigned short* kb, unsigned short* vb,
    const int* __restrict__ flag)
{
  if (*flag) return;
  const int y = blockIdx.y;
  const void* so = (y==0)?qso:((y==1)?kso:vso);
  const void* ro = (y==0)?qro:((y==1)?kro:vro);
  void* out = (y==0)?(void*)qb:((y==1)?(void*)kb:(void*)vb);
  stageB_body<false>(ttg, hhg, rules, so, ro, sel + y*1024, out, y, (y<2)?1:0, (y>=1)?1:0);
}

__global__ __launch_bounds__(256) void B_o_bf16(
    const float* ttg, const float* hhg, const int* rules,
    const void* oso, const void* oro, const float* sel, void* out,
    const int* __restrict__ flag)
{
  if (!*flag) return;
  stageB_body<true>(ttg, hhg, rules, oso, oro, sel, out, 0, 0, 1);
}

__global__ __launch_bounds__(256) void B_o_f32(
    const float* ttg, const float* hhg, const int* rules,
    const void* oso, const void* oro, const float* sel, void* out,
    const int* __restrict__ flag)
{
  if (*flag) return;
  stageB_body<false>(ttg, hhg, rules, oso, oro, sel, out, 0, 0, 0);
}

// ---------------------------------------------------------------------------
// Router mask — one 64-thread wave per (b,q); LDS-atomic histogram with
// barrier before read.
// ---------------------------------------------------------------------------
__global__ __launch_bounds__(64) void mask_kernel(
    const int* __restrict__ rules, const float* __restrict__ M,
    unsigned short* __restrict__ list, int* __restrict__ cntout)
{
  const int bid = blockIdx.x;              // b*1024 + qi
  const int b = bid >> 10, qi = bid & 1023;
  const int lane = threadIdx.x;
  __shared__ int rrow[SS];
  __shared__ float val[64];
  __shared__ int cnth[64];
  for (int i = lane; i < SS/4; i += 64)
    ((int4*)rrow)[i] = ((const int4*)(rules + b*SS))[i];
  cnth[lane] = 0;
  __syncthreads();                          // rrow + cnth=0 visible
  for (int k = lane; k <= qi; k += 64) atomicAdd(&cnth[rrow[k]], 1);
  const int qrule = rrow[qi];
  const float myv = M[qrule*64 + lane];
  val[lane] = myv;
  __syncthreads();                          // histogram + val visible
  const int c = cnth[lane];
  int A = 0;
  for (int r = 0; r < 64; r++) {
    int cr = __shfl(c, r);
    A += (val[r] > myv) ? cr : 0;
  }
  unsigned long long allowed = __ballot(A < 32);
  unsigned short* lp = list + (size_t)bid*SS;
  int pos = 0;
  const unsigned long long lmask = (1ULL << lane) - 1ULL;
  for (int k0 = 0; k0 <= qi; k0 += 64) {
    int k = k0 + lane;
    int kc = (k <= qi) ? k : qi;
    bool ok = (k <= qi) && (((allowed >> rrow[kc]) & 1ULL) != 0ULL);
    unsigned long long bal = __ballot(ok);
    if (ok) lp[pos + __popcll(bal & lmask)] = (unsigned short)k;
    pos += __popcll(bal);
  }
  if (lane == 0) cntout[bid] = pos;
}

// ---------------------------------------------------------------------------
// Sparse attention: block = (b, q, head-group of 4); 4 waves, one head each.
// keyl padded to 64-multiple -> uniform PV loop, no clamp, all shfl lanes
// active (R8 lesson). Dword-level bf16 unpack.
// ---------------------------------------------------------------------------
__global__ __launch_bounds__(256) void attn_kernel(
    const float* __restrict__ qb,
    const unsigned short* __restrict__ kb, const unsigned short* __restrict__ vb,
    const unsigned short* __restrict__ list, const int* __restrict__ cnt,
    float* __restrict__ outb)
{
  const int qi = blockIdx.x, b = blockIdx.y, hg = blockIdx.z;
  const int tid = threadIdx.x, lane = tid & 63, w = tid >> 6;
  const int nq = b*SS + qi;
  const int h = hg*4 + w;
  __shared__ unsigned short keyl[SS + 64];
  __shared__ float qs[4][64];
  const int total = cnt[nq];
  const int padded = (total + 63) & ~63;
  const unsigned short* lp = list + (size_t)nq*SS;
  for (int i = tid; i < total; i += 256) keyl[i] = lp[i];
  if (total < padded) {
    unsigned short k0 = lp[0];
    for (int i = total + tid; i < padded; i += 256) keyl[i] = k0;
  }
  qs[w][lane] = qb[(size_t)nq*D_MODEL + h*HEAD_DIM + lane] * 0.125f;
  __syncthreads();

  const unsigned short* kbase = kb + (size_t)b*SS*D_MODEL + h*HEAD_DIM;
  const unsigned short* vbase = vb + (size_t)b*SS*D_MODEL + h*HEAD_DIM;
  const int g = lane >> 4, d4 = lane & 15;
  float4 acc = {0.f,0.f,0.f,0.f};
  float m = -1e30f, l = 0.f;
  for (int c0 = 0; c0 < total; c0 += 64) {
    int nc = total - c0; if (nc > 64) nc = 64;
    float s = -1e30f;
    if (lane < nc) {
      int key = keyl[c0 + lane];
      const uint2* kr = (const uint2*)(kbase + (size_t)key*D_MODEL);
      float sum = 0.f;
      #pragma unroll
      for (int t = 0; t < 16; t++) {
        uint2 kw = kr[t];
        float4 qv = *(const float4*)&qs[w][4*t];  // LDS broadcast
        sum += qv.x*u2f(kw.x << 16) + qv.y*u2f(kw.x & 0xffff0000u)
             + qv.z*u2f(kw.y << 16) + qv.w*u2f(kw.y & 0xffff0000u);
      }
      s = sum;
    }
    float cm = s;
    #pragma unroll
    for (int off = 32; off; off >>= 1) cm = fmaxf(cm, __shfl_xor(cm, off));
    float newm = fmaxf(m, cm);
    float alpha = expf(m - newm);
    float ww = (lane < nc) ? expf(s - newm) : 0.f;
    float lsum = ww;
    #pragma unroll
    for (int off = 32; off; off >>= 1) lsum += __shfl_xor(lsum, off);
    l = l*alpha + lsum;
    m = newm;
    acc.x *= alpha; acc.y *= alpha; acc.z *= alpha; acc.w *= alpha;
    #pragma unroll 4
    for (int it = 0; it < 16; it++) {
      int i = g + it*4;
      float wi = __shfl(ww, i);
      int key = keyl[c0 + i];
      uint2 vw = *(const uint2*)(vbase + (size_t)key*D_MODEL + d4*4);
      acc.x += wi*u2f(vw.x << 16); acc.y += wi*u2f(vw.x & 0xffff0000u);
      acc.z += wi*u2f(vw.y << 16); acc.w += wi*u2f(vw.y & 0xffff0000u);
    }
  }
  acc.x += __shfl_xor(acc.x, 16); acc.y += __shfl_xor(acc.y, 16);
  acc.z += __shfl_xor(acc.z, 16); acc.w += __shfl_xor(acc.w, 16);
  acc.x += __shfl_xor(acc.x, 32); acc.y += __shfl_xor(acc.y, 32);
  acc.z += __shfl_xor(acc.z, 32); acc.w += __shfl_xor(acc.w, 32);
  if (lane < 16) {
    float invl = 1.0f / l;
    float4 o;
    o.x = acc.x*invl; o.y = acc.y*invl; o.z = acc.z*invl; o.w = acc.w*invl;
    *(float4*)(outb + (size_t)nq*D_MODEL + h*HEAD_DIM + d4*4) = o;
  }
}

// ---------------------------------------------------------------------------
extern "C" void kernel_launch(void* const* d_in, const int* in_sizes, int n_in,
                              void* d_out, int out_size, void* d_ws, size_t ws_size,
                              hipStream_t stream) {
  (void)in_sizes; (void)n_in; (void)out_size; (void)ws_size;
  const void* x    = d_in[0];
  const int* rules = (const int*)d_in[1];
  const void* q_si = d_in[2];  const void* q_so = d_in[3];
  const void* q_ri = d_in[4];  const void* q_ro = d_in[5];  const void* q_lg = d_in[6];
  const void* k_si = d_in[7];  const void* k_so = d_in[8];
  const void* k_ri = d_in[9];  const void* k_ro = d_in[10]; const void* k_lg = d_in[11];
  const void* v_si = d_in[12]; const void* v_so = d_in[13];
  const void* v_ri = d_in[14]; const void* v_ro = d_in[15]; const void* v_lg = d_in[16];
  const void* o_si = d_in[17]; const void* o_so = d_in[18];
  const void* o_ri = d_in[19]; const void* o_ro = d_in[20]; const void* o_lg = d_in[21];
  const void* rq   = d_in[22]; const void* rk   = d_in[23];

  char* ws = (char*)d_ws;
  const size_t MB = 1024*1024;
  float*          qb    = (float*)(ws);                     // 16 MB fp32 (also attn out, in-place)
  unsigned short* kb    = (unsigned short*)(ws + 16*MB);    // 8 MB bf16
  unsigned short* vb    = (unsigned short*)(ws + 24*MB);    // 8 MB bf16
  unsigned short* listb = (unsigned short*)(ws + 32*MB);    // 8 MB
  float*          ttg   = (float*)(ws + 40*MB);             // 1.5 MB
  float*          hhg   = (float*)(ws + 42*MB);             // 6.3 MB
  int*            cntb  = (int*)  (ws + 49*MB);             // 16 KB
  float*          Mt    = (float*)(ws + 49*MB + 16*1024);   // 16 KB
  float*          selt  = (float*)(ws + 49*MB + 32*1024);   // 16 KB
  int*            flag  = (int*)  (ws + 49*MB + 48*1024);

  detect_kernel<<<1, 64, 0, stream>>>((const unsigned short*)x, flag);
  precompute_kernel<<<1, 256, 0, stream>>>(rq, rk, q_lg, k_lg, v_lg, o_lg, Mt, selt, flag);

  A_qkv_bf16<<<dim3(NGRP, 3), 256, 0, stream>>>(x, rules, q_si, q_ri, k_si, k_ri, v_si, v_ri, ttg, hhg, flag);
  A_qkv_f32 <<<dim3(NGRP, 3), 256, 0, stream>>>(x, rules, q_si, q_ri, k_si, k_ri, v_si, v_ri, ttg, hhg, flag);
  B_qkv_bf16<<<dim3(NGRP, 3), 256, 0, stream>>>(ttg, hhg, rules, q_so, q_ro, k_so, k_ro, v_so, v_ro,
                                                selt, qb, kb, vb, flag);
  B_qkv_f32 <<<dim3(NGRP, 3), 256, 0, stream>>>(ttg, hhg, rules, q_so, q_ro, k_so, k_ro, v_so, v_ro,
                                                selt, qb, kb, vb, flag);
  mask_kernel<<<NTOK, 64, 0, stream>>>(rules, Mt, listb, cntb);
  attn_kernel<<<dim3(SS, BB, 4), 256, 0, stream>>>(qb, kb, vb, listb, cntb, qb);

  // o-projection: stage A (fp32 input from attn), then stage B to d_out
  A_o_bf16<<<dim3(NGRP, 1), 256, 0, stream>>>(qb, rules, o_si, o_ri, ttg, hhg, flag);
  A_qkv_f32<<<dim3(NGRP, 1), 256, 0, stream>>>(qb, rules, o_si, o_ri, o_si, o_ri, o_si, o_ri, ttg, hhg, flag);
  B_o_bf16<<<NGRP, 256, 0, stream>>>(ttg, hhg, rules, o_so, o_ro, selt + 3*1024, d_out, flag);
  B_o_f32 <<<NGRP, 256, 0, stream>>>(ttg, hhg, rules, o_so, o_ro, selt + 3*1024, d_out, flag);
}

// Round 13
// 322.538 us; speedup vs baseline: 1.1562x; 1.0279x over previous
//
#include <hip/hip_runtime.h>
#include <hip/hip_bf16.h>

#define D_MODEL 1024
#define N_HEADS 16
#define HEAD_DIM 64
#define NUM_RULES 64
#define RANK 8
#define SHARED_RANK 32
#define NUM_BLOCKS_ 16
#define BB 4
#define SS 1024
#define NTOK (BB*SS)
#define NGRP (NTOK/8)   // 512 token-groups of 8 (stage A)
#define NGRP4 (NTOK/4)  // 1024 blocks of 4 tokens (stage B)

__device__ __forceinline__ float bf2f(unsigned short u) {
  unsigned int i = ((unsigned int)u) << 16;
  float f;
  __builtin_memcpy(&f, &i, 4);
  return f;
}
__device__ __forceinline__ unsigned short f2bf(float f) {
  __hip_bfloat16 h = __float2bfloat16(f);
  unsigned short u;
  __builtin_memcpy(&u, &h, 2);
  return u;
}
__device__ __forceinline__ float u2f(unsigned int i) {
  float f;
  __builtin_memcpy(&f, &i, 4);
  return f;
}
template<bool BF>
__device__ __forceinline__ float ldw(const void* p, size_t i) {
  if (BF) return bf2f(((const unsigned short*)p)[i]);
  else    return ((const float*)p)[i];
}

// ---------------------------------------------------------------------------
// Dtype detection
// ---------------------------------------------------------------------------
__global__ void detect_kernel(const unsigned short* __restrict__ x, int* __restrict__ flag) {
  const int lane = threadIdx.x;  // 64
  int good = 0;
  for (int i = 0; i < 4; i++) {
    unsigned short u = x[lane*4 + i];
    int e = (u >> 7) & 0xFF;
    good += (e == 0 || (e >= 100 && e <= 145)) ? 1 : 0;
  }
  for (int off = 32; off; off >>= 1) good += __shfl_xor(good, off);
  if (lane == 0) flag[0] = (good >= 224) ? 1 : 0;
}

// ---------------------------------------------------------------------------
// Precompute: M[64][64] and sel[4][64][16]
// ---------------------------------------------------------------------------
template<bool BF>
__device__ __forceinline__ void precompute_body(
    const void* rq, const void* rk,
    const void* qlg, const void* klg, const void* vlg, const void* olg,
    float* __restrict__ M, float* __restrict__ sel)
{
  __shared__ float rqn[64][8], rkn[64][8];
  const int tid = threadIdx.x;  // 256
  if (tid < 64) {
    float v[8]; float s = 0.f;
    for (int i = 0; i < 8; i++) { v[i] = ldw<BF>(rq, tid*8+i); s += v[i]*v[i]; }
    float inv = 1.0f / fmaxf(sqrtf(s), 1e-12f);
    for (int i = 0; i < 8; i++) rqn[tid][i] = v[i]*inv;
  } else if (tid < 128) {
    int r = tid - 64;
    float v[8]; float s = 0.f;
    for (int i = 0; i < 8; i++) { v[i] = ldw<BF>(rk, r*8+i); s += v[i]*v[i]; }
    float inv = 1.0f / fmaxf(sqrtf(s), 1e-12f);
    for (int i = 0; i < 8; i++) rkn[r][i] = v[i]*inv;
  }
  __syncthreads();
  const float LN8 = 2.0794415416798357f;  // 1/tau = ln(8)
  for (int idx = tid; idx < 64*64; idx += 256) {
    int i = idx >> 6, j = idx & 63;
    float d = 0.f;
    for (int t = 0; t < 8; t++) d += rqn[i][t]*rkn[j][t];
    M[idx] = d * LN8;
  }
  const void* lgs[4] = {qlg, klg, vlg, olg};
  {
    int r = tid & 63;
    const void* lg = lgs[tid >> 6];
    float e[NUM_BLOCKS_]; float mx = -1e30f;
    for (int b = 0; b < NUM_BLOCKS_; b++) {
      e[b] = ldw<BF>(lg, r*NUM_BLOCKS_ + b) * 4.0f;
      mx = fmaxf(mx, e[b]);
    }
    float s = 0.f;
    for (int b = 0; b < NUM_BLOCKS_; b++) { e[b] = expf(e[b]-mx); s += e[b]; }
    float inv = 1.0f/s;
    for (int b = 0; b < NUM_BLOCKS_; b++) sel[tid*NUM_BLOCKS_+b] = e[b]*inv;
  }
}

__global__ void precompute_kernel(
    const void* rq, const void* rk,
    const void* qlg, const void* klg, const void* vlg, const void* olg,
    float* M, float* sel, const int* __restrict__ flag)
{
  if (*flag) precompute_body<true >(rq, rk, qlg, klg, vlg, olg, M, sel);
  else       precompute_body<false>(rq, rk, qlg, klg, vlg, olg, M, sel);
}

// ---------------------------------------------------------------------------
// Stage A: tt[n][32] = x[n]@si, hh[n][16][8] = per-rule lowrank inner.
// 8 tokens/block, 256 threads. ONE template instantiation per __global__.
// ---------------------------------------------------------------------------
template<bool IN_BF, bool W_BF>
__device__ __forceinline__ void stageA_body(
    const void* __restrict__ xin, const int* __restrict__ rules,
    const void* __restrict__ si, const void* __restrict__ ri,
    float* __restrict__ ttg, float* __restrict__ hhg, int yslot)
{
  const int g = blockIdx.x, n0 = g*8, tid = threadIdx.x;
  __shared__ float xs[8][D_MODEL];     // 32 KB
  __shared__ float tpart[8][32][9];    // pad 9: conflict-free reduce
  __shared__ int rl[8];

  #pragma unroll
  for (int t = 0; t < 8; t++) {
    float4 f;
    if (IN_BF) {
      ushort4 u = ((const ushort4*)((const unsigned short*)xin + (size_t)(n0+t)*D_MODEL))[tid];
      f.x = bf2f(u.x); f.y = bf2f(u.y); f.z = bf2f(u.z); f.w = bf2f(u.w);
    } else {
      f = ((const float4*)xin)[(size_t)(n0+t)*(D_MODEL/4) + tid];
    }
    *(float4*)&xs[t][tid*4] = f;
  }
  if (tid < 8) rl[tid] = rules[n0 + tid];
  __syncthreads();

  {
    const int c = tid >> 5, j = tid & 31;
    float p[8];
    #pragma unroll
    for (int t = 0; t < 8; t++) p[t] = 0.f;
    #pragma unroll 4
    for (int d4 = 0; d4 < 32; d4++) {
      const int d = c*128 + d4*4;
      float w0 = ldw<W_BF>(si, (size_t)(d+0)*SHARED_RANK + j);
      float w1 = ldw<W_BF>(si, (size_t)(d+1)*SHARED_RANK + j);
      float w2 = ldw<W_BF>(si, (size_t)(d+2)*SHARED_RANK + j);
      float w3 = ldw<W_BF>(si, (size_t)(d+3)*SHARED_RANK + j);
      #pragma unroll
      for (int t = 0; t < 8; t++) {
        float4 xv = *(const float4*)&xs[t][d];   // broadcast across j-lanes
        p[t] += xv.x*w0 + xv.y*w1 + xv.z*w2 + xv.w*w3;
      }
    }
    #pragma unroll
    for (int t = 0; t < 8; t++) tpart[c][j][t] = p[t];
  }
  __syncthreads();

  {
    const int t = tid >> 5, j = tid & 31;
    float s = 0.f;
    #pragma unroll
    for (int c = 0; c < 8; c++) s += tpart[c][j][t];
    ttg[(size_t)(yslot*NGRP + g)*256 + j*8 + t] = s;
  }
  {
    const int t = tid >> 5, blk = (tid >> 1) & 15, r0 = (tid & 1)*4;
    const int rule = rl[t];
    float a0=0.f, a1=0.f, a2=0.f, a3=0.f;
    #pragma unroll 4
    for (int k4 = 0; k4 < 16; k4++) {
      const int kk = ((k4 + blk) & 15) * 4;   // rotate: spreads LDS banks
      float4 xv = *(const float4*)&xs[t][blk*64 + kk];
      #pragma unroll
      for (int q = 0; q < 4; q++) {
        const int k = kk + q;
        float w0,w1,w2,w3;
        if (W_BF) {
          ushort4 u = *(const ushort4*)((const unsigned short*)ri + (size_t)rule*512 + (size_t)k*8 + r0);
          w0=bf2f(u.x); w1=bf2f(u.y); w2=bf2f(u.z); w3=bf2f(u.w);
        } else {
          float4 u = *(const float4*)((const float*)ri + (size_t)rule*512 + (size_t)k*8 + r0);
          w0=u.x; w1=u.y; w2=u.z; w3=u.w;
        }
        float xq = (q==0)?xv.x:((q==1)?xv.y:((q==2)?xv.z:xv.w));
        a0 += xq*w0; a1 += xq*w1; a2 += xq*w2; a3 += xq*w3;
      }
    }
    float4 hv; hv.x=a0; hv.y=a1; hv.z=a2; hv.w=a3;
    *(float4*)&hhg[((size_t)yslot*NTOK + n0 + t)*128 + blk*8 + r0] = hv;
  }
}

__global__ __launch_bounds__(256) void A_qkv_bf16(
    const void* x, const int* rules,
    const void* qsi, const void* qri, const void* ksi, const void* kri,
    const void* vsi, const void* vri,
    float* ttg, float* hhg, const int* __restrict__ flag)
{
  if (!*flag) return;
  const int y = blockIdx.y;
  const void* si = (y==0)?qsi:((y==1)?ksi:vsi);
  const void* ri = (y==0)?qri:((y==1)?kri:vri);
  stageA_body<true,true>(x, rules, si, ri, ttg, hhg, y);
}

__global__ __launch_bounds__(256) void A_qkv_f32(
    const void* x, const int* rules,
    const void* qsi, const void* qri, const void* ksi, const void* kri,
    const void* vsi, const void* vri,
    float* ttg, float* hhg, const int* __restrict__ flag)
{
  if (*flag) return;
  const int y = blockIdx.y;
  const void* si = (y==0)?qsi:((y==1)?ksi:vsi);
  const void* ri = (y==0)?qri:((y==1)?kri:vri);
  stageA_body<false,false>(x, rules, si, ri, ttg, hhg, y);
}

// o-projection stage A with bf16 weights but fp32 input (attn output)
__global__ __launch_bounds__(256) void A_o_bf16(
    const void* ain, const int* rules, const void* osi, const void* ori,
    float* ttg, float* hhg, const int* __restrict__ flag)
{
  if (!*flag) return;
  stageA_body<false,true>(ain, rules, osi, ori, ttg, hhg, 0);
}

// ---------------------------------------------------------------------------
// Stage B: 4 tokens/block (R12: 8-token version was stuck at ~82 µs,
// VGPR 208 / 10% occupancy — 32 accumulators + deep epilogue kept the live
// set large regardless of unroll caps. Halving tokens/block halves the
// accumulator file to 16 VGPRs and doubles block count; per-token arithmetic
// order unchanged -> bit-identical output.)
// Thread = 4 consecutive channels (ch0 = tid*4); so loads coalesced.
// ---------------------------------------------------------------------------
template<bool W_BF>
__device__ __forceinline__ void stageB_body(
    const float* __restrict__ ttg, const float* __restrict__ hhg,
    const int* __restrict__ rules,
    const void* __restrict__ so, const void* __restrict__ ro,
    const float* __restrict__ sel, void* __restrict__ out,
    int yslot, int do_rope, int out_bf)
{
  const int blk4 = blockIdx.x;            // 4-token block
  const int g8 = blk4 >> 1, half = blk4 & 1;
  const int n0 = blk4*4, tid = threadIdx.x;
  __shared__ float tt_lds[32][5];    // [j][t4], pad 5
  __shared__ float hh_lds[4][132];   // [t4][blk*8+r]
  __shared__ int rl[4];

  if (tid < 128) {                    // tt: 32 j x 4 tokens
    const int j = tid >> 2, t4 = tid & 3;
    tt_lds[j][t4] = ttg[(size_t)(yslot*NGRP + g8)*256 + j*8 + half*4 + t4];
  } else if (tid < 256 && (tid - 128) < 128) {  // hh: 4 tokens x 128 floats, float4 per thread
    const int i = tid - 128;
    const int t4 = i >> 5, c = (i*4) & 127;
    float4 hv = *(const float4*)&hhg[((size_t)yslot*NTOK + n0 + t4)*128 + c];
    *(float4*)&hh_lds[t4][c] = hv;
  }
  if (tid < 4) rl[tid] = rules[n0 + tid];
  __syncthreads();

  const int ch0 = tid*4;
  float a0[4], a1[4], a2[4], a3[4];
  #pragma unroll
  for (int t = 0; t < 4; t++) { a0[t]=0.f; a1[t]=0.f; a2[t]=0.f; a3[t]=0.f; }

  #pragma unroll 4
  for (int j = 0; j < 32; j++) {
    float w0, w1, w2, w3;
    if (W_BF) {
      ushort4 u = *(const ushort4*)((const unsigned short*)so + (size_t)j*D_MODEL + ch0);
      w0=bf2f(u.x); w1=bf2f(u.y); w2=bf2f(u.z); w3=bf2f(u.w);
    } else {
      float4 u = *(const float4*)((const float*)so + (size_t)j*D_MODEL + ch0);
      w0=u.x; w1=u.y; w2=u.z; w3=u.w;
    }
    #pragma unroll
    for (int t = 0; t < 4; t++) {
      float tv = tt_lds[j][t];         // LDS broadcast
      a0[t] += tv*w0; a1[t] += tv*w1; a2[t] += tv*w2; a3[t] += tv*w3;
    }
  }

  const int blk = ch0 >> 6, tc = ch0 & 63;
  float inv0 = 0.f, inv1 = 0.f;
  if (do_rope) {
    inv0 = expf(-(float)tc     * (9.210340371976184f/64.0f));   // 2*i0 == tc
    inv1 = expf(-(float)(tc+2) * (9.210340371976184f/64.0f));
  }
  #pragma unroll 2
  for (int t = 0; t < 4; t++) {
    const int rule = rl[t];
    float b0=0.f, b1=0.f, b2=0.f, b3=0.f;
    #pragma unroll
    for (int r = 0; r < 8; r++) {
      float w0,w1,w2,w3;
      if (W_BF) {
        ushort4 u = *(const ushort4*)((const unsigned short*)ro + (size_t)rule*512 + r*64 + tc);
        w0=bf2f(u.x); w1=bf2f(u.y); w2=bf2f(u.z); w3=bf2f(u.w);
      } else {
        float4 u = *(const float4*)((const float*)ro + (size_t)rule*512 + r*64 + tc);
        w0=u.x; w1=u.y; w2=u.z; w3=u.w;
      }
      float hv = hh_lds[t][blk*8 + r];
      b0 += hv*w0; b1 += hv*w1; b2 += hv*w2; b3 += hv*w3;
    }
    float sb = sel[rule*NUM_BLOCKS_ + blk];
    float e0 = a0[t] + b0*sb, o0 = a1[t] + b1*sb;
    float e1 = a2[t] + b2*sb, o1 = a3[t] + b3*sb;
    const int n = n0 + t;
    if (do_rope) {
      float spos = (float)(n & (SS-1));
      float sn0, cs0, sn1, cs1;
      sincosf(spos*inv0, &sn0, &cs0);
      sincosf(spos*inv1, &sn1, &cs1);
      float u0 = e0*cs0 - o0*sn0; o0 = o0*cs0 + e0*sn0; e0 = u0;
      float u1 = e1*cs1 - o1*sn1; o1 = o1*cs1 + e1*sn1; e1 = u1;
    }
    if (out_bf) {
      ushort4 uv; uv.x=f2bf(e0); uv.y=f2bf(o0); uv.z=f2bf(e1); uv.w=f2bf(o1);
      *(ushort4*)((unsigned short*)out + (size_t)n*D_MODEL + ch0) = uv;
    } else {
      float4 fv; fv.x=e0; fv.y=o0; fv.z=e1; fv.w=o1;
      *(float4*)((float*)out + (size_t)n*D_MODEL + ch0) = fv;
    }
  }
}

__global__ __launch_bounds__(256) void B_qkv_bf16(
    const float* ttg, const float* hhg, const int* rules,
    const void* qso, const void* qro, const void* kso, const void* kro,
    const void* vso, const void* vro,
    const float* sel, float* qb, unsigned short* kb, unsigned short* vb,
    const int* __restrict__ flag)
{
  if (!*flag) return;
  const int y = blockIdx.y;
  const void* so = (y==0)?qso:((y==1)?kso:vso);
  const void* ro = (y==0)?qro:((y==1)?kro:vro);
  void* out = (y==0)?(void*)qb:((y==1)?(void*)kb:(void*)vb);
  stageB_body<true>(ttg, hhg, rules, so, ro, sel + y*1024, out, y, (y<2)?1:0, (y>=1)?1:0);
}

__global__ __launch_bounds__(256) void B_qkv_f32(
    const float* ttg, const float* hhg, const int* rules,
    const void* qso, const void* qro, const void* kso, const void* kro,
    const void* vso, const void* vro,
    const float* sel, float* qb, unsigned short* kb, unsigned short* vb,
    const int* __restrict__ flag)
{
  if (*flag) return;
  const int y = blockIdx.y;
  const void* so = (y==0)?qso:((y==1)?kso:vso);
  const void* ro = (y==0)?qro:((y==1)?kro:vro);
  void* out = (y==0)?(void*)qb:((y==1)?(void*)kb:(void*)vb);
  stageB_body<false>(ttg, hhg, rules, so, ro, sel + y*1024, out, y, (y<2)?1:0, (y>=1)?1:0);
}

__global__ __launch_bounds__(256) void B_o_bf16(
    const float* ttg, const float* hhg, const int* rules,
    const void* oso, const void* oro, const float* sel, void* out,
    const int* __restrict__ flag)
{
  if (!*flag) return;
  stageB_body<true>(ttg, hhg, rules, oso, oro, sel, out, 0, 0, 1);
}

__global__ __launch_bounds__(256) void B_o_f32(
    const float* ttg, const float* hhg, const int* rules,
    const void* oso, const void* oro, const float* sel, void* out,
    const int* __restrict__ flag)
{
  if (*flag) return;
  stageB_body<false>(ttg, hhg, rules, oso, oro, sel, out, 0, 0, 0);
}

// ---------------------------------------------------------------------------
// Router mask — one 64-thread wave per (b,q); LDS-atomic histogram with
// barrier before read.
// ---------------------------------------------------------------------------
__global__ __launch_bounds__(64) void mask_kernel(
    const int* __restrict__ rules, const float* __restrict__ M,
    unsigned short* __restrict__ list, int* __restrict__ cntout)
{
  const int bid = blockIdx.x;              // b*1024 + qi
  const int b = bid >> 10, qi = bid & 1023;
  const int lane = threadIdx.x;
  __shared__ int rrow[SS];
  __shared__ float val[64];
  __shared__ int cnth[64];
  for (int i = lane; i < SS/4; i += 64)
    ((int4*)rrow)[i] = ((const int4*)(rules + b*SS))[i];
  cnth[lane] = 0;
  __syncthreads();                          // rrow + cnth=0 visible
  for (int k = lane; k <= qi; k += 64) atomicAdd(&cnth[rrow[k]], 1);
  const int qrule = rrow[qi];
  const float myv = M[qrule*64 + lane];
  val[lane] = myv;
  __syncthreads();                          // histogram + val visible
  const int c = cnth[lane];
  int A = 0;
  for (int r = 0; r < 64; r++) {
    int cr = __shfl(c, r);
    A += (val[r] > myv) ? cr : 0;
  }
  unsigned long long allowed = __ballot(A < 32);
  unsigned short* lp = list + (size_t)bid*SS;
  int pos = 0;
  const unsigned long long lmask = (1ULL << lane) - 1ULL;
  for (int k0 = 0; k0 <= qi; k0 += 64) {
    int k = k0 + lane;
    int kc = (k <= qi) ? k : qi;
    bool ok = (k <= qi) && (((allowed >> rrow[kc]) & 1ULL) != 0ULL);
    unsigned long long bal = __ballot(ok);
    if (ok) lp[pos + __popcll(bal & lmask)] = (unsigned short)k;
    pos += __popcll(bal);
  }
  if (lane == 0) cntout[bid] = pos;
}

// ---------------------------------------------------------------------------
// Sparse attention: block = (b, q, head-group of 4); 4 waves, one head each.
// keyl padded to 64-multiple -> uniform PV loop, all shfl lanes active
// (R8 lesson). QK loads widened to uint4 (8x16B vs 16x8B gathers).
// ---------------------------------------------------------------------------
__global__ __launch_bounds__(256) void attn_kernel(
    const float* __restrict__ qb,
    const unsigned short* __restrict__ kb, const unsigned short* __restrict__ vb,
    const unsigned short* __restrict__ list, const int* __restrict__ cnt,
    float* __restrict__ outb)
{
  const int qi = blockIdx.x, b = blockIdx.y, hg = blockIdx.z;
  const int tid = threadIdx.x, lane = tid & 63, w = tid >> 6;
  const int nq = b*SS + qi;
  const int h = hg*4 + w;
  __shared__ unsigned short keyl[SS + 64];
  __shared__ float qs[4][64];
  const int total = cnt[nq];
  const int padded = (total + 63) & ~63;
  const unsigned short* lp = list + (size_t)nq*SS;
  for (int i = tid; i < total; i += 256) keyl[i] = lp[i];
  if (total < padded) {
    unsigned short k0 = lp[0];
    for (int i = total + tid; i < padded; i += 256) keyl[i] = k0;
  }
  qs[w][lane] = qb[(size_t)nq*D_MODEL + h*HEAD_DIM + lane] * 0.125f;
  __syncthreads();

  const unsigned short* kbase = kb + (size_t)b*SS*D_MODEL + h*HEAD_DIM;
  const unsigned short* vbase = vb + (size_t)b*SS*D_MODEL + h*HEAD_DIM;
  const int g = lane >> 4, d4 = lane & 15;
  float4 acc = {0.f,0.f,0.f,0.f};
  float m = -1e30f, l = 0.f;
  for (int c0 = 0; c0 < total; c0 += 64) {
    int nc = total - c0; if (nc > 64) nc = 64;
    float s = -1e30f;
    if (lane < nc) {
      int key = keyl[c0 + lane];
      const uint4* kr = (const uint4*)(kbase + (size_t)key*D_MODEL);
      float sum = 0.f;
      #pragma unroll
      for (int t = 0; t < 8; t++) {
        uint4 kw = kr[t];
        float4 qv0 = *(const float4*)&qs[w][8*t];      // LDS broadcast
        float4 qv1 = *(const float4*)&qs[w][8*t + 4];
        sum += qv0.x*u2f(kw.x << 16) + qv0.y*u2f(kw.x & 0xffff0000u)
             + qv0.z*u2f(kw.y << 16) + qv0.w*u2f(kw.y & 0xffff0000u)
             + qv1.x*u2f(kw.z << 16) + qv1.y*u2f(kw.z & 0xffff0000u)
             + qv1.z*u2f(kw.w << 16) + qv1.w*u2f(kw.w & 0xffff0000u);
      }
      s = sum;
    }
    float cm = s;
    #pragma unroll
    for (int off = 32; off; off >>= 1) cm = fmaxf(cm, __shfl_xor(cm, off));
    float newm = fmaxf(m, cm);
    float alpha = expf(m - newm);
    float ww = (lane < nc) ? expf(s - newm) : 0.f;
    float lsum = ww;
    #pragma unroll
    for (int off = 32; off; off >>= 1) lsum += __shfl_xor(lsum, off);
    l = l*alpha + lsum;
    m = newm;
    acc.x *= alpha; acc.y *= alpha; acc.z *= alpha; acc.w *= alpha;
    #pragma unroll 4
    for (int it = 0; it < 16; it++) {
      int i = g + it*4;
      float wi = __shfl(ww, i);
      int key = keyl[c0 + i];
      uint2 vw = *(const uint2*)(vbase + (size_t)key*D_MODEL + d4*4);
      acc.x += wi*u2f(vw.x << 16); acc.y += wi*u2f(vw.x & 0xffff0000u);
      acc.z += wi*u2f(vw.y << 16); acc.w += wi*u2f(vw.y & 0xffff0000u);
    }
  }
  acc.x += __shfl_xor(acc.x, 16); acc.y += __shfl_xor(acc.y, 16);
  acc.z += __shfl_xor(acc.z, 16); acc.w += __shfl_xor(acc.w, 16);
  acc.x += __shfl_xor(acc.x, 32); acc.y += __shfl_xor(acc.y, 32);
  acc.z += __shfl_xor(acc.z, 32); acc.w += __shfl_xor(acc.w, 32);
  if (lane < 16) {
    float invl = 1.0f / l;
    float4 o;
    o.x = acc.x*invl; o.y = acc.y*invl; o.z = acc.z*invl; o.w = acc.w*invl;
    *(float4*)(outb + (size_t)nq*D_MODEL + h*HEAD_DIM + d4*4) = o;
  }
}

// ---------------------------------------------------------------------------
extern "C" void kernel_launch(void* const* d_in, const int* in_sizes, int n_in,
                              void* d_out, int out_size, void* d_ws, size_t ws_size,
                              hipStream_t stream) {
  (void)in_sizes; (void)n_in; (void)out_size; (void)ws_size;
  const void* x    = d_in[0];
  const int* rules = (const int*)d_in[1];
  const void* q_si = d_in[2];  const void* q_so = d_in[3];
  const void* q_ri = d_in[4];  const void* q_ro = d_in[5];  const void* q_lg = d_in[6];
  const void* k_si = d_in[7];  const void* k_so = d_in[8];
  const void* k_ri = d_in[9];  const void* k_ro = d_in[10]; const void* k_lg = d_in[11];
  const void* v_si = d_in[12]; const void* v_so = d_in[13];
  const void* v_ri = d_in[14]; const void* v_ro = d_in[15]; const void* v_lg = d_in[16];
  const void* o_si = d_in[17]; const void* o_so = d_in[18];
  const void* o_ri = d_in[19]; const void* o_ro = d_in[20]; const void* o_lg = d_in[21];
  const void* rq   = d_in[22]; const void* rk   = d_in[23];

  char* ws = (char*)d_ws;
  const size_t MB = 1024*1024;
  float*          qb    = (float*)(ws);                     // 16 MB fp32 (also attn out, in-place)
  unsigned short* kb    = (unsigned short*)(ws + 16*MB);    // 8 MB bf16
  unsigned short* vb    = (unsigned short*)(ws + 24*MB);    // 8 MB bf16
  unsigned short* listb = (unsigned short*)(ws + 32*MB);    // 8 MB
  float*          ttg   = (float*)(ws + 40*MB);             // 1.5 MB
  float*          hhg   = (float*)(ws + 42*MB);             // 6.3 MB
  int*            cntb  = (int*)  (ws + 49*MB);             // 16 KB
  float*          Mt    = (float*)(ws + 49*MB + 16*1024);   // 16 KB
  float*          selt  = (float*)(ws + 49*MB + 32*1024);   // 16 KB
  int*            flag  = (int*)  (ws + 49*MB + 48*1024);

  detect_kernel<<<1, 64, 0, stream>>>((const unsigned short*)x, flag);
  precompute_kernel<<<1, 256, 0, stream>>>(rq, rk, q_lg, k_lg, v_lg, o_lg, Mt, selt, flag);

  A_qkv_bf16<<<dim3(NGRP, 3), 256, 0, stream>>>(x, rules, q_si, q_ri, k_si, k_ri, v_si, v_ri, ttg, hhg, flag);
  A_qkv_f32 <<<dim3(NGRP, 3), 256, 0, stream>>>(x, rules, q_si, q_ri, k_si, k_ri, v_si, v_ri, ttg, hhg, flag);
  B_qkv_bf16<<<dim3(NGRP4, 3), 256, 0, stream>>>(ttg, hhg, rules, q_so, q_ro, k_so, k_ro, v_so, v_ro,
                                                 selt, qb, kb, vb, flag);
  B_qkv_f32 <<<dim3(NGRP4, 3), 256, 0, stream>>>(ttg, hhg, rules, q_so, q_ro, k_so, k_ro, v_so, v_ro,
                                                 selt, qb, kb, vb, flag);
  mask_kernel<<<NTOK, 64, 0, stream>>>(rules, Mt, listb, cntb);
  attn_kernel<<<dim3(SS, BB, 4), 256, 0, stream>>>(qb, kb, vb, listb, cntb, qb);

  // o-projection: stage A (fp32 input from attn), then stage B to d_out
  A_o_bf16<<<dim3(NGRP, 1), 256, 0, stream>>>(qb, rules, o_si, o_ri, ttg, hhg, flag);
  A_qkv_f32<<<dim3(NGRP, 1), 256, 0, stream>>>(qb, rules, o_si, o_ri, o_si, o_ri, o_si, o_ri, ttg, hhg, flag);
  B_o_bf16<<<NGRP4, 256, 0, stream>>>(ttg, hhg, rules, o_so, o_ro, selt + 3*1024, d_out, flag);
  B_o_f32 <<<NGRP4, 256, 0, stream>>>(ttg, hhg, rules, o_so, o_ro, selt + 3*1024, d_out, flag);
}